// Round 1
// 391.266 us; speedup vs baseline: 3.2472x; 3.2472x over previous
//
#include <hip/hip_runtime.h>

// ---------------------------------------------------------------------------
// SAGE-LSTM on MI355X.
// Xpre = x@Wih^T + b precomputed per layer (hoists input GEMM out of the
// 16-step recurrence). LSTM: gates^T = Whh.h^T with MFMA 16x16x32 bf16,
// Whh fragment-packed in LDS (prescaled log2e/2log2e), h LDS round-trip.
//
// R2: lstm was memory-bound on the random Xpre gather (2.44 TB/s, MfmaUtil 3%).
//  - Xpre stored fp16 (not fp32): halves gather bytes, working set 20.5 MB
//    fits L2s far better (refetch ratio should drop).
//  - Xpre layout [n][kt][quad][gate][4]: each lane's 16 C-init values per kt
//    are 32 contiguous bytes -> 2 dwordx4 loads (16 loads/lane/step, was 32).
//  - 1-step-ahead register prefetch: pX[16] uint4 buffer, slot kt refilled
//    with step t+1's data right after its cvt in step t (loads hide under a
//    full step of MFMA). +64 VGPRs is free: occupancy is LDS-bound at
//    1 block/CU; __launch_bounds__(320,2) caps VGPR at 256 so the 5-wave
//    block stays schedulable.
// ---------------------------------------------------------------------------

#define NN   20000
#define L2E  1.4426950408889634f

typedef unsigned short u16;
typedef __attribute__((ext_vector_type(8))) short frag8;     // 8 x bf16
typedef __attribute__((ext_vector_type(4))) float facc4;     // 4 x f32 acc
typedef __attribute__((ext_vector_type(8))) _Float16 half8;  // 8 x fp16

// ---- workspace layout (bytes) ----
#define OFF_X16   0u
#define OFF_H1    5120000u
#define OFF_HN    10240000u
#define OFF_WIH1P 15360000u
#define OFF_WHH1P 15491072u
#define OFF_WIH2P 15622144u
#define OFF_WHH2P 15753216u
#define OFF_WS1P  15884288u
#define OFF_WN1P  15917056u
#define OFF_WS2B  15949824u
#define OFF_WN2B  15950080u
#define OFF_B1    15950336u
#define OFF_B2    15952384u
#define OFF_XPRE  15954432u   // fp16 [NN,512] = 20,480,000 B

__device__ __forceinline__ u16 f2bf(float f) {
  union { float f; unsigned u; } v; v.f = f;
  unsigned r = (v.u + 0x7fffu + ((v.u >> 16) & 1u)) >> 16;  // RNE
  return (u16)r;
}
__device__ __forceinline__ float bflo(unsigned u) {
  union { unsigned u; float f; } v; v.u = u << 16; return v.f;
}
__device__ __forceinline__ float bfhi(unsigned u) {
  union { unsigned u; float f; } v; v.u = u & 0xffff0000u; return v.f;
}
__device__ __forceinline__ unsigned pk2h(float a, float b) {
  union { _Float16 h[2]; unsigned u; } v;
  v.h[0] = (_Float16)a; v.h[1] = (_Float16)b;
  return v.u;
}
__device__ __forceinline__ facc4 mfma16(frag8 a, frag8 b, facc4 c) {
  return __builtin_amdgcn_mfma_f32_16x16x32_bf16(a, b, c, 0, 0, 0);
}
// x prescaled by L2E: sigmoid(x) = 1/(1+2^-xp)
__device__ __forceinline__ float sigm_ps(float xp) {
  return __builtin_amdgcn_rcpf(1.f + __builtin_amdgcn_exp2f(-xp));
}
// x prescaled by 2*L2E: tanh(x) = 1 - 2/(1+2^xp)
__device__ __forceinline__ float tanh_ps(float xp) {
  return 1.f - 2.f * __builtin_amdgcn_rcpf(1.f + __builtin_amdgcn_exp2f(xp));
}
__device__ __forceinline__ float gate_scale(int row) {
  return (row >= 256 && row < 384) ? 2.f * L2E : L2E;  // g-gate rows get 2*log2e
}

// pack [R,128] fp32 row-major -> A-fragment order: dst[i] where
// i = ((tj*4+kb)*64 + lane)*8 + e ; A[row = tj*16+(lane&15)][k = kb*32+(lane>>4)*8+e]
__device__ __forceinline__ void pack512(u16* dst, const float* src, int i) {
  int e = i & 7, ln = (i >> 3) & 63, kb = (i >> 9) & 3, tj = i >> 11;
  int row = tj * 16 + (ln & 15);
  int col = kb * 32 + (ln >> 4) * 8 + e;
  dst[i] = f2bf(src[row * 128 + col] * gate_scale(row));
}
__device__ __forceinline__ void pack128(u16* dst, const float* src, int i) {
  int e = i & 7, ln = (i >> 3) & 63, kb = (i >> 9) & 3, tj = i >> 11;
  dst[i] = f2bf(src[(tj * 16 + (ln & 15)) * 128 + kb * 32 + (ln >> 4) * 8 + e]);
}

__global__ __launch_bounds__(256) void pack_kernel(
    const float* __restrict__ x,
    const float* __restrict__ Wih1, const float* __restrict__ Whh1,
    const float* __restrict__ bih1, const float* __restrict__ bhh1,
    const float* __restrict__ Wself1, const float* __restrict__ Wneigh1,
    const float* __restrict__ Wih2, const float* __restrict__ Whh2,
    const float* __restrict__ bih2, const float* __restrict__ bhh2,
    const float* __restrict__ Wself2, const float* __restrict__ Wneigh2,
    char* __restrict__ ws)
{
  int i = blockIdx.x * 256 + threadIdx.x;
  if (i < 2560000) { ((u16*)(ws + OFF_X16))[i] = f2bf(x[i]); return; }
  i -= 2560000;
  if (i < 65536) { pack512((u16*)(ws + OFF_WIH1P), Wih1, i); return; }
  i -= 65536;
  if (i < 65536) { pack512((u16*)(ws + OFF_WHH1P), Whh1, i); return; }
  i -= 65536;
  if (i < 65536) { pack512((u16*)(ws + OFF_WIH2P), Wih2, i); return; }
  i -= 65536;
  if (i < 65536) { pack512((u16*)(ws + OFF_WHH2P), Whh2, i); return; }
  i -= 65536;
  if (i < 16384) { pack128((u16*)(ws + OFF_WS1P), Wself1, i); return; }
  i -= 16384;
  if (i < 16384) { pack128((u16*)(ws + OFF_WN1P), Wneigh1, i); return; }
  i -= 16384;
  if (i < 128) { ((u16*)(ws + OFF_WS2B))[i] = f2bf(Wself2[i]); return; }
  i -= 128;
  if (i < 128) { ((u16*)(ws + OFF_WN2B))[i] = f2bf(Wneigh2[i]); return; }
  i -= 128;
  if (i < 512) { ((float*)(ws + OFF_B1))[i] = (bih1[i] + bhh1[i]) * gate_scale(i); return; }
  i -= 512;
  if (i < 512) { ((float*)(ws + OFF_B2))[i] = (bih2[i] + bhh2[i]) * gate_scale(i); }
}

// Xpre[n] = inp[n] @ W^T + bias, stored fp16 in gather-friendly layout:
// element offset = n*512 + kt*64 + quad*16 + gate*4 + r
// (gate-row j = tj*16 + quad*4 + r decomposes as gate=tj>>3, kt=tj&7)
__global__ __launch_bounds__(256) void xpre_kernel(
    const u16* __restrict__ inp,    // [NN,128] bf16
    const frag8* __restrict__ Wp,   // 8192 frags
    const float* __restrict__ bias, // [512] fp32 prescaled
    u16* __restrict__ outp)         // [NN,512] fp16 packed
{
  const int lane = threadIdx.x & 63, wave = threadIdx.x >> 6;
  const int m = lane & 15, quad = lane >> 4;
  const int node_base = (blockIdx.x * 4 + wave) * 16;
  if (node_base >= NN) return;
  const int row = node_base + m;
  frag8 bfr[4];
#pragma unroll
  for (int kb = 0; kb < 4; ++kb)
    bfr[kb] = *(const frag8*)(inp + (size_t)row * 128 + kb * 32 + quad * 8);
#pragma unroll
  for (int tj = 0; tj < 32; ++tj) {
    float4 bv = *(const float4*)(bias + tj * 16 + quad * 4);
    facc4 acc = {bv.x, bv.y, bv.z, bv.w};
#pragma unroll
    for (int kb = 0; kb < 4; ++kb)
      acc = mfma16(Wp[(tj * 4 + kb) * 64 + lane], bfr[kb], acc);
    uint2 st = { pk2h(acc[0], acc[1]), pk2h(acc[2], acc[3]) };
    *(uint2*)(outp + (size_t)row * 512 + (tj & 7) * 64 + quad * 16 + (tj >> 3) * 4) = st;
  }
}

// 16-step LSTM over gathered neighbor sequences; final h -> hN (bf16).
__global__ __launch_bounds__(320, 2) void lstm_kernel(
    const u16* __restrict__ Xpre,   // [NN,512] fp16 packed, prescaled, bias folded
    const frag8* __restrict__ Wp,   // packed Whh, 8192 frags (128 KB)
    const int* __restrict__ nbr,    // [NN,16]
    u16* __restrict__ hN)           // [NN,128] bf16
{
  __shared__ frag8 Wlds[8192];                       // 131072 B
  __shared__ __align__(16) u16 h_lds[5][16 * 136];   // 21760 B (pad 136: 2-way banks)
  const int tid = threadIdx.x;
  const int lane = tid & 63, wave = tid >> 6;
  const int m = lane & 15, quad = lane >> 4;

  for (int i = tid; i < 8192; i += 320) Wlds[i] = Wp[i];
  u16* hl = h_lds[wave];
  for (int i = lane; i < 16 * 136; i += 64) hl[i] = 0;
  __syncthreads();

  const int node_base = (blockIdx.x * 5 + wave) * 16;   // 250*5*16 == 20000 exact
  // lane holds nbr[node_base + m][quad*4 + s], s=0..3
  int4 idx4 = *(const int4*)(nbr + (size_t)(node_base + m) * 16 + quad * 4);

  facc4 c[8];
#pragma unroll
  for (int kt = 0; kt < 8; ++kt) c[kt] = (facc4){0.f, 0.f, 0.f, 0.f};

  // base pointer (as uint4) of this lane's neighbor row at step t
  auto xrow4 = [&](int t) -> const uint4* {
    const int tq = t >> 2, ts = t & 3;
    int sel = (ts == 0) ? idx4.x : (ts == 1) ? idx4.y : (ts == 2) ? idx4.z : idx4.w;
    int idx = __shfl(sel, m + (tq << 4), 64);         // neighbor of node m at step t
    return (const uint4*)(Xpre + (size_t)idx * 512);
  };

  // 1-step-ahead register prefetch buffer: slot kt holds {gates01, gates23}
  uint4 pX[16];
  {
    const uint4* p0 = xrow4(0);
#pragma unroll
    for (int q = 0; q < 8; ++q) {
      pX[2 * q]     = p0[q * 8 + quad * 2];
      pX[2 * q + 1] = p0[q * 8 + quad * 2 + 1];
    }
  }

#pragma unroll 1
  for (int t = 0; t < 16; ++t) {
    const uint4* pn = xrow4(t < 15 ? t + 1 : 15);     // final prefetch re-reads t=15 (cache hit)

    frag8 bfr[4];                                     // B = h (prev step) from LDS
#pragma unroll
    for (int kb = 0; kb < 4; ++kb)
      bfr[kb] = *(const frag8*)(hl + m * 136 + kb * 32 + quad * 8);

#pragma unroll
    for (int kt = 0; kt < 8; ++kt) {
      union { uint4 u; half8 h; } ua, ub;
      ua.u = pX[2 * kt];
      ub.u = pX[2 * kt + 1];
      facc4 ai = {(float)ua.h[0], (float)ua.h[1], (float)ua.h[2], (float)ua.h[3]};
      facc4 af = {(float)ua.h[4], (float)ua.h[5], (float)ua.h[6], (float)ua.h[7]};
      facc4 ag = {(float)ub.h[0], (float)ub.h[1], (float)ub.h[2], (float)ub.h[3]};
      facc4 ao = {(float)ub.h[4], (float)ub.h[5], (float)ub.h[6], (float)ub.h[7]};
      // refill this slot with step t+1's data: hides under the MFMA stream
      pX[2 * kt]     = pn[kt * 8 + quad * 2];
      pX[2 * kt + 1] = pn[kt * 8 + quad * 2 + 1];
#pragma unroll
      for (int kb = 0; kb < 4; ++kb) {
        ai = mfma16(Wlds[((0 * 8 + kt) * 4 + kb) * 64 + lane], bfr[kb], ai);
        af = mfma16(Wlds[((1 * 8 + kt) * 4 + kb) * 64 + lane], bfr[kb], af);
        ag = mfma16(Wlds[((2 * 8 + kt) * 4 + kb) * 64 + lane], bfr[kb], ag);
        ao = mfma16(Wlds[((3 * 8 + kt) * 4 + kb) * 64 + lane], bfr[kb], ao);
      }
      facc4 hv;
#pragma unroll
      for (int r = 0; r < 4; ++r) {
        float si = sigm_ps(ai[r]);
        float sf = sigm_ps(af[r]);
        float tg = tanh_ps(ag[r]);
        float cn = sf * c[kt][r] + si * tg;
        c[kt][r] = cn;
        float so = sigm_ps(ao[r]);
        hv[r] = so * tanh_ps((2.f * L2E) * cn);
      }
      uint2 hp;
      hp.x = (unsigned)f2bf(hv[0]) | ((unsigned)f2bf(hv[1]) << 16);
      hp.y = (unsigned)f2bf(hv[2]) | ((unsigned)f2bf(hv[3]) << 16);
      *(uint2*)(hl + m * 136 + kt * 16 + quad * 4) = hp;
    }
  }
#pragma unroll
  for (int kt = 0; kt < 8; ++kt) {
    uint2 hp = *(const uint2*)(hl + m * 136 + kt * 16 + quad * 4);
    *(uint2*)(hN + (size_t)(node_base + m) * 128 + kt * 16 + quad * 4) = hp;
  }
}

// h1 = relu(x@Wself^T + hN@Wneigh^T + bneigh), bf16 out. 8 j-tiles.
__global__ __launch_bounds__(256) void out1_kernel(
    const u16* __restrict__ x16, const u16* __restrict__ hN,
    const frag8* __restrict__ Wsp, const frag8* __restrict__ Wnp,
    const float* __restrict__ bneigh, u16* __restrict__ h1)
{
  const int lane = threadIdx.x & 63, wave = threadIdx.x >> 6;
  const int m = lane & 15, quad = lane >> 4;
  const int node_base = (blockIdx.x * 4 + wave) * 16;
  if (node_base >= NN) return;
  const int row = node_base + m;
  frag8 bx[4], bh[4];
#pragma unroll
  for (int kb = 0; kb < 4; ++kb) {
    bx[kb] = *(const frag8*)(x16 + (size_t)row * 128 + kb * 32 + quad * 8);
    bh[kb] = *(const frag8*)(hN + (size_t)row * 128 + kb * 32 + quad * 8);
  }
#pragma unroll
  for (int tj = 0; tj < 8; ++tj) {
    float4 bv = *(const float4*)(bneigh + tj * 16 + quad * 4);
    facc4 acc = {bv.x, bv.y, bv.z, bv.w};
#pragma unroll
    for (int kb = 0; kb < 4; ++kb) {
      acc = mfma16(Wsp[(tj * 4 + kb) * 64 + lane], bx[kb], acc);
      acc = mfma16(Wnp[(tj * 4 + kb) * 64 + lane], bh[kb], acc);
    }
#pragma unroll
    for (int r = 0; r < 4; ++r) acc[r] = fmaxf(acc[r], 0.f);
    uint2 st;
    st.x = (unsigned)f2bf(acc[0]) | ((unsigned)f2bf(acc[1]) << 16);
    st.y = (unsigned)f2bf(acc[2]) | ((unsigned)f2bf(acc[3]) << 16);
    *(uint2*)(h1 + (size_t)row * 128 + tj * 16 + quad * 4) = st;
  }
}

__device__ __forceinline__ float dot2(unsigned a, unsigned b) {
  return bflo(a) * bflo(b) + bfhi(a) * bfhi(b);
}

// out[n] = sigmoid(h1[n].Wself2 + hN2[n].Wneigh2 + b), fp32 out
__global__ __launch_bounds__(256) void out2_kernel(
    const u16* __restrict__ h1, const u16* __restrict__ hN2,
    const u16* __restrict__ ws2, const u16* __restrict__ wn2,
    const float* __restrict__ b2, float* __restrict__ outp)
{
  int n = blockIdx.x * 256 + threadIdx.x;
  if (n >= NN) return;
  const uint4* r1 = (const uint4*)(h1 + (size_t)n * 128);
  const uint4* r2 = (const uint4*)(hN2 + (size_t)n * 128);
  const uint4* w1 = (const uint4*)ws2;
  const uint4* w2 = (const uint4*)wn2;
  float acc = b2[0];
#pragma unroll
  for (int q = 0; q < 16; ++q) {   // 16 uint4 = 128 features
    uint4 a = r1[q], w = w1[q];
    acc += dot2(a.x, w.x) + dot2(a.y, w.y) + dot2(a.z, w.z) + dot2(a.w, w.w);
    uint4 c = r2[q], v = w2[q];
    acc += dot2(c.x, v.x) + dot2(c.y, v.y) + dot2(c.z, v.z) + dot2(c.w, v.w);
  }
  outp[n] = __builtin_amdgcn_rcpf(1.f + __builtin_amdgcn_exp2f(-acc * L2E));
}

extern "C" void kernel_launch(void* const* d_in, const int* in_sizes, int n_in,
                              void* d_out, int out_size, void* d_ws, size_t ws_size,
                              hipStream_t stream) {
  const float* x       = (const float*)d_in[0];
  const int*   nbr     = (const int*)d_in[1];
  const float* Wih1    = (const float*)d_in[2];
  const float* Whh1    = (const float*)d_in[3];
  const float* bih1    = (const float*)d_in[4];
  const float* bhh1    = (const float*)d_in[5];
  const float* Wself1  = (const float*)d_in[6];
  const float* Wneigh1 = (const float*)d_in[7];
  const float* bneigh1 = (const float*)d_in[8];
  const float* Wih2    = (const float*)d_in[9];
  const float* Whh2    = (const float*)d_in[10];
  const float* bih2    = (const float*)d_in[11];
  const float* bhh2    = (const float*)d_in[12];
  const float* Wself2  = (const float*)d_in[13];
  const float* Wneigh2 = (const float*)d_in[14];
  const float* bneigh2 = (const float*)d_in[15];

  char* ws = (char*)d_ws;
  u16*   x16   = (u16*)(ws + OFF_X16);
  u16*   h1    = (u16*)(ws + OFF_H1);
  u16*   hN    = (u16*)(ws + OFF_HN);
  u16*   Xpre  = (u16*)(ws + OFF_XPRE);
  frag8* Wih1p = (frag8*)(ws + OFF_WIH1P);
  frag8* Whh1p = (frag8*)(ws + OFF_WHH1P);
  frag8* Wih2p = (frag8*)(ws + OFF_WIH2P);
  frag8* Whh2p = (frag8*)(ws + OFF_WHH2P);
  frag8* Ws1p  = (frag8*)(ws + OFF_WS1P);
  frag8* Wn1p  = (frag8*)(ws + OFF_WN1P);
  u16*   Ws2b  = (u16*)(ws + OFF_WS2B);
  u16*   Wn2b  = (u16*)(ws + OFF_WN2B);
  float* b1    = (float*)(ws + OFF_B1);
  float* b2    = (float*)(ws + OFF_B2);

  pack_kernel<<<11157, 256, 0, stream>>>(x, Wih1, Whh1, bih1, bhh1, Wself1,
                                         Wneigh1, Wih2, Whh2, bih2, bhh2,
                                         Wself2, Wneigh2, ws);
  // layer 1
  xpre_kernel<<<313, 256, 0, stream>>>(x16, Wih1p, b1, Xpre);
  lstm_kernel<<<250, 320, 0, stream>>>(Xpre, Whh1p, nbr, hN);
  out1_kernel<<<313, 256, 0, stream>>>(x16, hN, Ws1p, Wn1p, bneigh1, h1);
  // layer 2
  xpre_kernel<<<313, 256, 0, stream>>>(h1, Wih2p, b2, Xpre);
  lstm_kernel<<<250, 320, 0, stream>>>(Xpre, Whh2p, nbr, hN);
  out2_kernel<<<79, 256, 0, stream>>>(h1, hN, Ws2b, Wn2b, bneigh2, (float*)d_out);
}

// Round 2
// 345.272 us; speedup vs baseline: 3.6798x; 1.1332x over previous
//
#include <hip/hip_runtime.h>

// ---------------------------------------------------------------------------
// SAGE-LSTM on MI355X.
// Xpre = x@Wih^T + b precomputed per layer (hoists input GEMM out of the
// 16-step recurrence). LSTM: gates^T = Whh.h^T with MFMA 16x16x32 bf16,
// Whh fragment-packed in LDS (prescaled log2e/2log2e), h LDS round-trip.
//
// R2: fp16 Xpre + gather-friendly layout + 1-step register prefetch
//     (565 -> 117 us/dispatch; FETCH 1.24 GB -> 131 MB, near L2 floor).
// R3: lstm was latency-bound at 1.25 waves/SIMD (VALUBusy 38%, MfmaUtil 15%,
//     no pipe saturated). Pair-split: 2 waves share one 16-node group,
//     wave half h = kt 0-3 / 4-7. Same 153 KB LDS, 10 waves/block
//     (2.5/SIMD), per-wave work halved. Per-step h exchange uses raw
//     lgkmcnt(0)+s_barrier (NOT __syncthreads) so prefetch vmcnt loads
//     stay in flight across the barriers.
// ---------------------------------------------------------------------------

#define NN   20000
#define L2E  1.4426950408889634f

typedef unsigned short u16;
typedef __attribute__((ext_vector_type(8))) short frag8;     // 8 x bf16
typedef __attribute__((ext_vector_type(4))) float facc4;     // 4 x f32 acc
typedef __attribute__((ext_vector_type(8))) _Float16 half8;  // 8 x fp16

// ---- workspace layout (bytes) ----
#define OFF_X16   0u
#define OFF_H1    5120000u
#define OFF_HN    10240000u
#define OFF_WIH1P 15360000u
#define OFF_WHH1P 15491072u
#define OFF_WIH2P 15622144u
#define OFF_WHH2P 15753216u
#define OFF_WS1P  15884288u
#define OFF_WN1P  15917056u
#define OFF_WS2B  15949824u
#define OFF_WN2B  15950080u
#define OFF_B1    15950336u
#define OFF_B2    15952384u
#define OFF_XPRE  15954432u   // fp16 [NN,512] = 20,480,000 B

__device__ __forceinline__ u16 f2bf(float f) {
  union { float f; unsigned u; } v; v.f = f;
  unsigned r = (v.u + 0x7fffu + ((v.u >> 16) & 1u)) >> 16;  // RNE
  return (u16)r;
}
__device__ __forceinline__ float bflo(unsigned u) {
  union { unsigned u; float f; } v; v.u = u << 16; return v.f;
}
__device__ __forceinline__ float bfhi(unsigned u) {
  union { unsigned u; float f; } v; v.u = u & 0xffff0000u; return v.f;
}
__device__ __forceinline__ unsigned pk2h(float a, float b) {
  union { _Float16 h[2]; unsigned u; } v;
  v.h[0] = (_Float16)a; v.h[1] = (_Float16)b;
  return v.u;
}
__device__ __forceinline__ facc4 mfma16(frag8 a, frag8 b, facc4 c) {
  return __builtin_amdgcn_mfma_f32_16x16x32_bf16(a, b, c, 0, 0, 0);
}
// x prescaled by L2E: sigmoid(x) = 1/(1+2^-xp)
__device__ __forceinline__ float sigm_ps(float xp) {
  return __builtin_amdgcn_rcpf(1.f + __builtin_amdgcn_exp2f(-xp));
}
// x prescaled by 2*L2E: tanh(x) = 1 - 2/(1+2^xp)
__device__ __forceinline__ float tanh_ps(float xp) {
  return 1.f - 2.f * __builtin_amdgcn_rcpf(1.f + __builtin_amdgcn_exp2f(xp));
}
__device__ __forceinline__ float gate_scale(int row) {
  return (row >= 256 && row < 384) ? 2.f * L2E : L2E;  // g-gate rows get 2*log2e
}

// pack [R,128] fp32 row-major -> A-fragment order: dst[i] where
// i = ((tj*4+kb)*64 + lane)*8 + e ; A[row = tj*16+(lane&15)][k = kb*32+(lane>>4)*8+e]
__device__ __forceinline__ void pack512(u16* dst, const float* src, int i) {
  int e = i & 7, ln = (i >> 3) & 63, kb = (i >> 9) & 3, tj = i >> 11;
  int row = tj * 16 + (ln & 15);
  int col = kb * 32 + (ln >> 4) * 8 + e;
  dst[i] = f2bf(src[row * 128 + col] * gate_scale(row));
}
__device__ __forceinline__ void pack128(u16* dst, const float* src, int i) {
  int e = i & 7, ln = (i >> 3) & 63, kb = (i >> 9) & 3, tj = i >> 11;
  dst[i] = f2bf(src[(tj * 16 + (ln & 15)) * 128 + kb * 32 + (ln >> 4) * 8 + e]);
}

__global__ __launch_bounds__(256) void pack_kernel(
    const float* __restrict__ x,
    const float* __restrict__ Wih1, const float* __restrict__ Whh1,
    const float* __restrict__ bih1, const float* __restrict__ bhh1,
    const float* __restrict__ Wself1, const float* __restrict__ Wneigh1,
    const float* __restrict__ Wih2, const float* __restrict__ Whh2,
    const float* __restrict__ bih2, const float* __restrict__ bhh2,
    const float* __restrict__ Wself2, const float* __restrict__ Wneigh2,
    char* __restrict__ ws)
{
  int i = blockIdx.x * 256 + threadIdx.x;
  if (i < 2560000) { ((u16*)(ws + OFF_X16))[i] = f2bf(x[i]); return; }
  i -= 2560000;
  if (i < 65536) { pack512((u16*)(ws + OFF_WIH1P), Wih1, i); return; }
  i -= 65536;
  if (i < 65536) { pack512((u16*)(ws + OFF_WHH1P), Whh1, i); return; }
  i -= 65536;
  if (i < 65536) { pack512((u16*)(ws + OFF_WIH2P), Wih2, i); return; }
  i -= 65536;
  if (i < 65536) { pack512((u16*)(ws + OFF_WHH2P), Whh2, i); return; }
  i -= 65536;
  if (i < 16384) { pack128((u16*)(ws + OFF_WS1P), Wself1, i); return; }
  i -= 16384;
  if (i < 16384) { pack128((u16*)(ws + OFF_WN1P), Wneigh1, i); return; }
  i -= 16384;
  if (i < 128) { ((u16*)(ws + OFF_WS2B))[i] = f2bf(Wself2[i]); return; }
  i -= 128;
  if (i < 128) { ((u16*)(ws + OFF_WN2B))[i] = f2bf(Wneigh2[i]); return; }
  i -= 128;
  if (i < 512) { ((float*)(ws + OFF_B1))[i] = (bih1[i] + bhh1[i]) * gate_scale(i); return; }
  i -= 512;
  if (i < 512) { ((float*)(ws + OFF_B2))[i] = (bih2[i] + bhh2[i]) * gate_scale(i); }
}

// Xpre[n] = inp[n] @ W^T + bias, stored fp16 in gather-friendly layout:
// element offset = n*512 + kt*64 + quad*16 + gate*4 + r
// (gate-row j = tj*16 + quad*4 + r decomposes as gate=tj>>3, kt=tj&7)
__global__ __launch_bounds__(256) void xpre_kernel(
    const u16* __restrict__ inp,    // [NN,128] bf16
    const frag8* __restrict__ Wp,   // 8192 frags
    const float* __restrict__ bias, // [512] fp32 prescaled
    u16* __restrict__ outp)         // [NN,512] fp16 packed
{
  const int lane = threadIdx.x & 63, wave = threadIdx.x >> 6;
  const int m = lane & 15, quad = lane >> 4;
  const int node_base = (blockIdx.x * 4 + wave) * 16;
  if (node_base >= NN) return;
  const int row = node_base + m;
  frag8 bfr[4];
#pragma unroll
  for (int kb = 0; kb < 4; ++kb)
    bfr[kb] = *(const frag8*)(inp + (size_t)row * 128 + kb * 32 + quad * 8);
#pragma unroll
  for (int tj = 0; tj < 32; ++tj) {
    float4 bv = *(const float4*)(bias + tj * 16 + quad * 4);
    facc4 acc = {bv.x, bv.y, bv.z, bv.w};
#pragma unroll
    for (int kb = 0; kb < 4; ++kb)
      acc = mfma16(Wp[(tj * 4 + kb) * 64 + lane], bfr[kb], acc);
    uint2 st = { pk2h(acc[0], acc[1]), pk2h(acc[2], acc[3]) };
    *(uint2*)(outp + (size_t)row * 512 + (tj & 7) * 64 + quad * 16 + (tj >> 3) * 4) = st;
  }
}

// 16-step LSTM over gathered neighbor sequences; final h -> hN (bf16).
// Pair-split: waves (2p, 2p+1) share node group p; half=wave&1 owns
// kt = half*4 .. half*4+3 (hidden units half*64 .. half*64+63).
__global__ __launch_bounds__(640) void lstm_kernel(
    const u16* __restrict__ Xpre,   // [NN,512] fp16 packed, prescaled, bias folded
    const frag8* __restrict__ Wp,   // packed Whh, 8192 frags (128 KB)
    const int* __restrict__ nbr,    // [NN,16]
    u16* __restrict__ hN)           // [NN,128] bf16
{
  __shared__ frag8 Wlds[8192];                       // 131072 B
  __shared__ __align__(16) u16 h_lds[5][16 * 136];   // 21760 B (pad 136: 2-way banks)
  const int tid = threadIdx.x;
  const int lane = tid & 63, wave = tid >> 6;
  const int pair = wave >> 1, half = wave & 1;
  const int m = lane & 15, quad = lane >> 4;
  const int ktbase = half * 4;

  for (int i = tid; i < 8192; i += 640) Wlds[i] = Wp[i];
  u16* hl = h_lds[pair];
  if (half == 0)
    for (int i = lane; i < 16 * 136; i += 64) hl[i] = 0;
  __syncthreads();

  const int node_base = (blockIdx.x * 5 + pair) * 16;   // 250*5*16 == 20000 exact
  // lane holds nbr[node_base + m][quad*4 + s], s=0..3
  int4 idx4 = *(const int4*)(nbr + (size_t)(node_base + m) * 16 + quad * 4);

  facc4 c[4];
#pragma unroll
  for (int lkt = 0; lkt < 4; ++lkt) c[lkt] = (facc4){0.f, 0.f, 0.f, 0.f};

  // base pointer (as uint4) of this lane's neighbor row at step t
  auto xrow4 = [&](int t) -> const uint4* {
    const int tq = t >> 2, ts = t & 3;
    int sel = (ts == 0) ? idx4.x : (ts == 1) ? idx4.y : (ts == 2) ? idx4.z : idx4.w;
    int idx = __shfl(sel, m + (tq << 4), 64);         // neighbor of node m at step t
    return (const uint4*)(Xpre + (size_t)idx * 512);
  };

  // 1-step-ahead register prefetch buffer: slot lkt holds {gates01, gates23}
  uint4 pX[8];
  {
    const uint4* p0 = xrow4(0);
#pragma unroll
    for (int q = 0; q < 4; ++q) {
      pX[2 * q]     = p0[(ktbase + q) * 8 + quad * 2];
      pX[2 * q + 1] = p0[(ktbase + q) * 8 + quad * 2 + 1];
    }
  }

#pragma unroll 1
  for (int t = 0; t < 16; ++t) {
    const uint4* pn = xrow4(t < 15 ? t + 1 : 15);     // final prefetch re-reads t=15 (cache hit)

    frag8 bfr[4];                                     // B = full h (prev step) from LDS
#pragma unroll
    for (int kb = 0; kb < 4; ++kb)
      bfr[kb] = *(const frag8*)(hl + m * 136 + kb * 32 + quad * 8);
    // all pair reads done before anyone overwrites h; LDS-only drain keeps
    // the vmcnt prefetch in flight across the barrier.
    asm volatile("s_waitcnt lgkmcnt(0)" ::: "memory");
    __builtin_amdgcn_s_barrier();

#pragma unroll
    for (int lkt = 0; lkt < 4; ++lkt) {
      const int kt = ktbase + lkt;
      union { uint4 u; half8 h; } ua, ub;
      ua.u = pX[2 * lkt];
      ub.u = pX[2 * lkt + 1];
      facc4 ai = {(float)ua.h[0], (float)ua.h[1], (float)ua.h[2], (float)ua.h[3]};
      facc4 af = {(float)ua.h[4], (float)ua.h[5], (float)ua.h[6], (float)ua.h[7]};
      facc4 ag = {(float)ub.h[0], (float)ub.h[1], (float)ub.h[2], (float)ub.h[3]};
      facc4 ao = {(float)ub.h[4], (float)ub.h[5], (float)ub.h[6], (float)ub.h[7]};
      // refill this slot with step t+1's data: hides under the MFMA stream
      pX[2 * lkt]     = pn[kt * 8 + quad * 2];
      pX[2 * lkt + 1] = pn[kt * 8 + quad * 2 + 1];
#pragma unroll
      for (int kb = 0; kb < 4; ++kb) {
        ai = mfma16(Wlds[((0 * 8 + kt) * 4 + kb) * 64 + lane], bfr[kb], ai);
        af = mfma16(Wlds[((1 * 8 + kt) * 4 + kb) * 64 + lane], bfr[kb], af);
        ag = mfma16(Wlds[((2 * 8 + kt) * 4 + kb) * 64 + lane], bfr[kb], ag);
        ao = mfma16(Wlds[((3 * 8 + kt) * 4 + kb) * 64 + lane], bfr[kb], ao);
      }
      facc4 hv;
#pragma unroll
      for (int r = 0; r < 4; ++r) {
        float si = sigm_ps(ai[r]);
        float sf = sigm_ps(af[r]);
        float tg = tanh_ps(ag[r]);
        float cn = sf * c[lkt][r] + si * tg;
        c[lkt][r] = cn;
        float so = sigm_ps(ao[r]);
        hv[r] = so * tanh_ps((2.f * L2E) * cn);
      }
      uint2 hp;
      hp.x = (unsigned)f2bf(hv[0]) | ((unsigned)f2bf(hv[1]) << 16);
      hp.y = (unsigned)f2bf(hv[2]) | ((unsigned)f2bf(hv[3]) << 16);
      *(uint2*)(hl + m * 136 + kt * 16 + quad * 4) = hp;
    }
    // pair's h half-writes visible before next step's reads
    asm volatile("s_waitcnt lgkmcnt(0)" ::: "memory");
    __builtin_amdgcn_s_barrier();
  }
#pragma unroll
  for (int lkt = 0; lkt < 4; ++lkt) {
    const int kt = ktbase + lkt;
    uint2 hp = *(const uint2*)(hl + m * 136 + kt * 16 + quad * 4);
    *(uint2*)(hN + (size_t)(node_base + m) * 128 + kt * 16 + quad * 4) = hp;
  }
}

// h1 = relu(x@Wself^T + hN@Wneigh^T + bneigh), bf16 out. 8 j-tiles.
__global__ __launch_bounds__(256) void out1_kernel(
    const u16* __restrict__ x16, const u16* __restrict__ hN,
    const frag8* __restrict__ Wsp, const frag8* __restrict__ Wnp,
    const float* __restrict__ bneigh, u16* __restrict__ h1)
{
  const int lane = threadIdx.x & 63, wave = threadIdx.x >> 6;
  const int m = lane & 15, quad = lane >> 4;
  const int node_base = (blockIdx.x * 4 + wave) * 16;
  if (node_base >= NN) return;
  const int row = node_base + m;
  frag8 bx[4], bh[4];
#pragma unroll
  for (int kb = 0; kb < 4; ++kb) {
    bx[kb] = *(const frag8*)(x16 + (size_t)row * 128 + kb * 32 + quad * 8);
    bh[kb] = *(const frag8*)(hN + (size_t)row * 128 + kb * 32 + quad * 8);
  }
#pragma unroll
  for (int tj = 0; tj < 8; ++tj) {
    float4 bv = *(const float4*)(bneigh + tj * 16 + quad * 4);
    facc4 acc = {bv.x, bv.y, bv.z, bv.w};
#pragma unroll
    for (int kb = 0; kb < 4; ++kb) {
      acc = mfma16(Wsp[(tj * 4 + kb) * 64 + lane], bx[kb], acc);
      acc = mfma16(Wnp[(tj * 4 + kb) * 64 + lane], bh[kb], acc);
    }
#pragma unroll
    for (int r = 0; r < 4; ++r) acc[r] = fmaxf(acc[r], 0.f);
    uint2 st;
    st.x = (unsigned)f2bf(acc[0]) | ((unsigned)f2bf(acc[1]) << 16);
    st.y = (unsigned)f2bf(acc[2]) | ((unsigned)f2bf(acc[3]) << 16);
    *(uint2*)(h1 + (size_t)row * 128 + tj * 16 + quad * 4) = st;
  }
}

__device__ __forceinline__ float dot2(unsigned a, unsigned b) {
  return bflo(a) * bflo(b) + bfhi(a) * bfhi(b);
}

// out[n] = sigmoid(h1[n].Wself2 + hN2[n].Wneigh2 + b), fp32 out
__global__ __launch_bounds__(256) void out2_kernel(
    const u16* __restrict__ h1, const u16* __restrict__ hN2,
    const u16* __restrict__ ws2, const u16* __restrict__ wn2,
    const float* __restrict__ b2, float* __restrict__ outp)
{
  int n = blockIdx.x * 256 + threadIdx.x;
  if (n >= NN) return;
  const uint4* r1 = (const uint4*)(h1 + (size_t)n * 128);
  const uint4* r2 = (const uint4*)(hN2 + (size_t)n * 128);
  const uint4* w1 = (const uint4*)ws2;
  const uint4* w2 = (const uint4*)wn2;
  float acc = b2[0];
#pragma unroll
  for (int q = 0; q < 16; ++q) {   // 16 uint4 = 128 features
    uint4 a = r1[q], w = w1[q];
    acc += dot2(a.x, w.x) + dot2(a.y, w.y) + dot2(a.z, w.z) + dot2(a.w, w.w);
    uint4 c = r2[q], v = w2[q];
    acc += dot2(c.x, v.x) + dot2(c.y, v.y) + dot2(c.z, v.z) + dot2(c.w, v.w);
  }
  outp[n] = __builtin_amdgcn_rcpf(1.f + __builtin_amdgcn_exp2f(-acc * L2E));
}

extern "C" void kernel_launch(void* const* d_in, const int* in_sizes, int n_in,
                              void* d_out, int out_size, void* d_ws, size_t ws_size,
                              hipStream_t stream) {
  const float* x       = (const float*)d_in[0];
  const int*   nbr     = (const int*)d_in[1];
  const float* Wih1    = (const float*)d_in[2];
  const float* Whh1    = (const float*)d_in[3];
  const float* bih1    = (const float*)d_in[4];
  const float* bhh1    = (const float*)d_in[5];
  const float* Wself1  = (const float*)d_in[6];
  const float* Wneigh1 = (const float*)d_in[7];
  const float* bneigh1 = (const float*)d_in[8];
  const float* Wih2    = (const float*)d_in[9];
  const float* Whh2    = (const float*)d_in[10];
  const float* bih2    = (const float*)d_in[11];
  const float* bhh2    = (const float*)d_in[12];
  const float* Wself2  = (const float*)d_in[13];
  const float* Wneigh2 = (const float*)d_in[14];
  const float* bneigh2 = (const float*)d_in[15];

  char* ws = (char*)d_ws;
  u16*   x16   = (u16*)(ws + OFF_X16);
  u16*   h1    = (u16*)(ws + OFF_H1);
  u16*   hN    = (u16*)(ws + OFF_HN);
  u16*   Xpre  = (u16*)(ws + OFF_XPRE);
  frag8* Wih1p = (frag8*)(ws + OFF_WIH1P);
  frag8* Whh1p = (frag8*)(ws + OFF_WHH1P);
  frag8* Wih2p = (frag8*)(ws + OFF_WIH2P);
  frag8* Whh2p = (frag8*)(ws + OFF_WHH2P);
  frag8* Ws1p  = (frag8*)(ws + OFF_WS1P);
  frag8* Wn1p  = (frag8*)(ws + OFF_WN1P);
  u16*   Ws2b  = (u16*)(ws + OFF_WS2B);
  u16*   Wn2b  = (u16*)(ws + OFF_WN2B);
  float* b1    = (float*)(ws + OFF_B1);
  float* b2    = (float*)(ws + OFF_B2);

  pack_kernel<<<11157, 256, 0, stream>>>(x, Wih1, Whh1, bih1, bhh1, Wself1,
                                         Wneigh1, Wih2, Whh2, bih2, bhh2,
                                         Wself2, Wneigh2, ws);
  // layer 1
  xpre_kernel<<<313, 256, 0, stream>>>(x16, Wih1p, b1, Xpre);
  lstm_kernel<<<250, 640, 0, stream>>>(Xpre, Whh1p, nbr, hN);
  out1_kernel<<<313, 256, 0, stream>>>(x16, hN, Ws1p, Wn1p, bneigh1, h1);
  // layer 2
  xpre_kernel<<<313, 256, 0, stream>>>(h1, Wih2p, b2, Xpre);
  lstm_kernel<<<250, 640, 0, stream>>>(Xpre, Whh2p, nbr, hN);
  out2_kernel<<<79, 256, 0, stream>>>(h1, hN, Ws2b, Wn2b, bneigh2, (float*)d_out);
}

// Round 3
// 311.646 us; speedup vs baseline: 4.0768x; 1.1079x over previous
//
#include <hip/hip_runtime.h>

// ---------------------------------------------------------------------------
// SAGE-LSTM on MI355X.
// Xpre = x@Wih^T + b precomputed per layer (hoists input GEMM out of the
// 16-step recurrence). LSTM: gates^T = Whh.h^T with MFMA 16x16x32 bf16.
//
// R2: fp16 Xpre + gather layout + 1-step register prefetch (565 -> 117 us).
// R3: pair-split 10 waves/block (117 -> 94 us) — still latency-bound;
//     LDS-pipe accounting showed Whh A-fragment ds_reads (64 x b128 per
//     wave-step) were ~50 us of per-CU LDS time, the largest pipe load.
// R4: Whh in REGISTERS. 8 waves per 16-node group; wave g owns kt-tile g
//     (units 16g..16g+15) for all 4 gates -> A-set = 16 frag8 = 64 VGPR,
//     loaded from global once, zero LDS A-traffic. No cross-wave gate
//     exchange needed. LDS = 2 x 4.25 KB double-buffered h -> ONE barrier
//     per step. __launch_bounds__(512,4) caps VGPR at 128 -> 16 waves/CU
//     (2 blocks). Final h written to hN straight from registers.
// ---------------------------------------------------------------------------

#define NN   20000
#define L2E  1.4426950408889634f

typedef unsigned short u16;
typedef __attribute__((ext_vector_type(8))) short frag8;     // 8 x bf16
typedef __attribute__((ext_vector_type(4))) float facc4;     // 4 x f32 acc
typedef __attribute__((ext_vector_type(8))) _Float16 half8;  // 8 x fp16

// ---- workspace layout (bytes) ----
#define OFF_X16   0u
#define OFF_H1    5120000u
#define OFF_HN    10240000u
#define OFF_WIH1P 15360000u
#define OFF_WHH1P 15491072u
#define OFF_WIH2P 15622144u
#define OFF_WHH2P 15753216u
#define OFF_WS1P  15884288u
#define OFF_WN1P  15917056u
#define OFF_WS2B  15949824u
#define OFF_WN2B  15950080u
#define OFF_B1    15950336u
#define OFF_B2    15952384u
#define OFF_XPRE  15954432u   // fp16 [NN,512] = 20,480,000 B

__device__ __forceinline__ u16 f2bf(float f) {
  union { float f; unsigned u; } v; v.f = f;
  unsigned r = (v.u + 0x7fffu + ((v.u >> 16) & 1u)) >> 16;  // RNE
  return (u16)r;
}
__device__ __forceinline__ float bflo(unsigned u) {
  union { unsigned u; float f; } v; v.u = u << 16; return v.f;
}
__device__ __forceinline__ float bfhi(unsigned u) {
  union { unsigned u; float f; } v; v.u = u & 0xffff0000u; return v.f;
}
__device__ __forceinline__ unsigned pk2h(float a, float b) {
  union { _Float16 h[2]; unsigned u; } v;
  v.h[0] = (_Float16)a; v.h[1] = (_Float16)b;
  return v.u;
}
__device__ __forceinline__ facc4 mfma16(frag8 a, frag8 b, facc4 c) {
  return __builtin_amdgcn_mfma_f32_16x16x32_bf16(a, b, c, 0, 0, 0);
}
// x prescaled by L2E: sigmoid(x) = 1/(1+2^-xp)
__device__ __forceinline__ float sigm_ps(float xp) {
  return __builtin_amdgcn_rcpf(1.f + __builtin_amdgcn_exp2f(-xp));
}
// x prescaled by 2*L2E: tanh(x) = 1 - 2/(1+2^xp)
__device__ __forceinline__ float tanh_ps(float xp) {
  return 1.f - 2.f * __builtin_amdgcn_rcpf(1.f + __builtin_amdgcn_exp2f(xp));
}
__device__ __forceinline__ float gate_scale(int row) {
  return (row >= 256 && row < 384) ? 2.f * L2E : L2E;  // g-gate rows get 2*log2e
}

// pack [R,128] fp32 row-major -> A-fragment order: dst[i] where
// i = ((tj*4+kb)*64 + lane)*8 + e ; A[row = tj*16+(lane&15)][k = kb*32+(lane>>4)*8+e]
__device__ __forceinline__ void pack512(u16* dst, const float* src, int i) {
  int e = i & 7, ln = (i >> 3) & 63, kb = (i >> 9) & 3, tj = i >> 11;
  int row = tj * 16 + (ln & 15);
  int col = kb * 32 + (ln >> 4) * 8 + e;
  dst[i] = f2bf(src[row * 128 + col] * gate_scale(row));
}
__device__ __forceinline__ void pack128(u16* dst, const float* src, int i) {
  int e = i & 7, ln = (i >> 3) & 63, kb = (i >> 9) & 3, tj = i >> 11;
  dst[i] = f2bf(src[(tj * 16 + (ln & 15)) * 128 + kb * 32 + (ln >> 4) * 8 + e]);
}

__global__ __launch_bounds__(256) void pack_kernel(
    const float* __restrict__ x,
    const float* __restrict__ Wih1, const float* __restrict__ Whh1,
    const float* __restrict__ bih1, const float* __restrict__ bhh1,
    const float* __restrict__ Wself1, const float* __restrict__ Wneigh1,
    const float* __restrict__ Wih2, const float* __restrict__ Whh2,
    const float* __restrict__ bih2, const float* __restrict__ bhh2,
    const float* __restrict__ Wself2, const float* __restrict__ Wneigh2,
    char* __restrict__ ws)
{
  int i = blockIdx.x * 256 + threadIdx.x;
  if (i < 2560000) { ((u16*)(ws + OFF_X16))[i] = f2bf(x[i]); return; }
  i -= 2560000;
  if (i < 65536) { pack512((u16*)(ws + OFF_WIH1P), Wih1, i); return; }
  i -= 65536;
  if (i < 65536) { pack512((u16*)(ws + OFF_WHH1P), Whh1, i); return; }
  i -= 65536;
  if (i < 65536) { pack512((u16*)(ws + OFF_WIH2P), Wih2, i); return; }
  i -= 65536;
  if (i < 65536) { pack512((u16*)(ws + OFF_WHH2P), Whh2, i); return; }
  i -= 65536;
  if (i < 16384) { pack128((u16*)(ws + OFF_WS1P), Wself1, i); return; }
  i -= 16384;
  if (i < 16384) { pack128((u16*)(ws + OFF_WN1P), Wneigh1, i); return; }
  i -= 16384;
  if (i < 128) { ((u16*)(ws + OFF_WS2B))[i] = f2bf(Wself2[i]); return; }
  i -= 128;
  if (i < 128) { ((u16*)(ws + OFF_WN2B))[i] = f2bf(Wneigh2[i]); return; }
  i -= 128;
  if (i < 512) { ((float*)(ws + OFF_B1))[i] = (bih1[i] + bhh1[i]) * gate_scale(i); return; }
  i -= 512;
  if (i < 512) { ((float*)(ws + OFF_B2))[i] = (bih2[i] + bhh2[i]) * gate_scale(i); }
}

// Xpre[n] = inp[n] @ W^T + bias, stored fp16 in gather-friendly layout:
// element offset = n*512 + kt*64 + quad*16 + gate*4 + r
// (gate-row j = tj*16 + quad*4 + r decomposes as gate=tj>>3, kt=tj&7)
__global__ __launch_bounds__(256) void xpre_kernel(
    const u16* __restrict__ inp,    // [NN,128] bf16
    const frag8* __restrict__ Wp,   // 8192 frags
    const float* __restrict__ bias, // [512] fp32 prescaled
    u16* __restrict__ outp)         // [NN,512] fp16 packed
{
  const int lane = threadIdx.x & 63, wave = threadIdx.x >> 6;
  const int m = lane & 15, quad = lane >> 4;
  const int node_base = (blockIdx.x * 4 + wave) * 16;
  if (node_base >= NN) return;
  const int row = node_base + m;
  frag8 bfr[4];
#pragma unroll
  for (int kb = 0; kb < 4; ++kb)
    bfr[kb] = *(const frag8*)(inp + (size_t)row * 128 + kb * 32 + quad * 8);
#pragma unroll
  for (int tj = 0; tj < 32; ++tj) {
    float4 bv = *(const float4*)(bias + tj * 16 + quad * 4);
    facc4 acc = {bv.x, bv.y, bv.z, bv.w};
#pragma unroll
    for (int kb = 0; kb < 4; ++kb)
      acc = mfma16(Wp[(tj * 4 + kb) * 64 + lane], bfr[kb], acc);
    uint2 st = { pk2h(acc[0], acc[1]), pk2h(acc[2], acc[3]) };
    *(uint2*)(outp + (size_t)row * 512 + (tj & 7) * 64 + quad * 16 + (tj >> 3) * 4) = st;
  }
}

// 16-step LSTM over gathered neighbor sequences; final h -> hN (bf16).
// 8 waves per 16-node group; wave g owns kt-tile g (units 16g..16g+15) for
// all 4 gates. Whh A-fragments live in registers (16 frag8 = 64 VGPR).
// h double-buffered in LDS -> one barrier per step.
__global__ __launch_bounds__(512, 4) void lstm_kernel(
    const u16* __restrict__ Xpre,   // [NN,512] fp16 packed, prescaled, bias folded
    const frag8* __restrict__ Wp,   // packed Whh, 8192 frags
    const int* __restrict__ nbr,    // [NN,16]
    u16* __restrict__ hN)           // [NN,128] bf16
{
  __shared__ __align__(16) u16 h_lds[2][16 * 136];   // 8704 B double-buffered h
  const int tid = threadIdx.x;
  const int lane = tid & 63, g = tid >> 6;          // wave g owns kt = g
  const int m = lane & 15, quad = lane >> 4;

  // A-fragments for kt=g: [gate][kb], resident in registers for all 16 steps.
  frag8 A[4][4];
#pragma unroll
  for (int gate = 0; gate < 4; ++gate)
#pragma unroll
    for (int kb = 0; kb < 4; ++kb)
      A[gate][kb] = Wp[((gate * 8 + g) * 4 + kb) * 64 + lane];

  for (int i = tid; i < 16 * 136; i += 512) h_lds[0][i] = 0;

  const int node_base = blockIdx.x * 16;             // 1250*16 == 20000 exact
  // lane holds nbr[node_base + m][quad*4 + s], s=0..3
  int4 idx4 = *(const int4*)(nbr + (size_t)(node_base + m) * 16 + quad * 4);

  facc4 c = {0.f, 0.f, 0.f, 0.f};

  // this lane's 32-byte Xpre slice (kt=g, quad) of neighbor at step t
  auto xslice = [&](int t) -> const uint4* {
    const int tq = t >> 2, ts = t & 3;
    int sel = (ts == 0) ? idx4.x : (ts == 1) ? idx4.y : (ts == 2) ? idx4.z : idx4.w;
    int idx = __shfl(sel, m + (tq << 4), 64);        // neighbor of node m at step t
    return (const uint4*)(Xpre + (size_t)idx * 512) + g * 8 + quad * 2;
  };

  uint4 pX0, pX1;                                    // 1-step-ahead prefetch
  { const uint4* p0 = xslice(0); pX0 = p0[0]; pX1 = p0[1]; }

  __syncthreads();                                   // h zeros + everyone ready

#pragma unroll 1
  for (int t = 0; t < 16; ++t) {
    const u16* hr = h_lds[t & 1];
    u16* hw = h_lds[(t + 1) & 1];
    const uint4* pn = xslice(t < 15 ? t + 1 : 15);   // t=15 re-read is an L2 hit

    frag8 bfr[4];                                    // B = full h (prev step)
#pragma unroll
    for (int kb = 0; kb < 4; ++kb)
      bfr[kb] = *(const frag8*)(hr + m * 136 + kb * 32 + quad * 8);

    union { uint4 u; half8 h; } ua, ub;
    ua.u = pX0; ub.u = pX1;
    facc4 ai = {(float)ua.h[0], (float)ua.h[1], (float)ua.h[2], (float)ua.h[3]};
    facc4 af = {(float)ua.h[4], (float)ua.h[5], (float)ua.h[6], (float)ua.h[7]};
    facc4 ag = {(float)ub.h[0], (float)ub.h[1], (float)ub.h[2], (float)ub.h[3]};
    facc4 ao = {(float)ub.h[4], (float)ub.h[5], (float)ub.h[6], (float)ub.h[7]};
    // refill prefetch: a full step of MFMA+VALU to hide under
    pX0 = pn[0]; pX1 = pn[1];

#pragma unroll
    for (int kb = 0; kb < 4; ++kb) {
      ai = mfma16(A[0][kb], bfr[kb], ai);
      af = mfma16(A[1][kb], bfr[kb], af);
      ag = mfma16(A[2][kb], bfr[kb], ag);
      ao = mfma16(A[3][kb], bfr[kb], ao);
    }

    facc4 hv;
#pragma unroll
    for (int r = 0; r < 4; ++r) {
      float si = sigm_ps(ai[r]);
      float sf = sigm_ps(af[r]);
      float tg = tanh_ps(ag[r]);
      float cn = sf * c[r] + si * tg;
      c[r] = cn;
      float so = sigm_ps(ao[r]);
      hv[r] = so * tanh_ps((2.f * L2E) * cn);
    }
    uint2 hp;
    hp.x = (unsigned)f2bf(hv[0]) | ((unsigned)f2bf(hv[1]) << 16);
    hp.y = (unsigned)f2bf(hv[2]) | ((unsigned)f2bf(hv[3]) << 16);

    if (t < 15) {
      *(uint2*)(hw + m * 136 + g * 16 + quad * 4) = hp;
      // LDS-only drain: prefetch vmcnt loads stay in flight across barrier
      asm volatile("s_waitcnt lgkmcnt(0)" ::: "memory");
      __builtin_amdgcn_s_barrier();
    } else {
      *(uint2*)(hN + (size_t)(node_base + m) * 128 + g * 16 + quad * 4) = hp;
    }
  }
}

// h1 = relu(x@Wself^T + hN@Wneigh^T + bneigh), bf16 out. 8 j-tiles.
__global__ __launch_bounds__(256) void out1_kernel(
    const u16* __restrict__ x16, const u16* __restrict__ hN,
    const frag8* __restrict__ Wsp, const frag8* __restrict__ Wnp,
    const float* __restrict__ bneigh, u16* __restrict__ h1)
{
  const int lane = threadIdx.x & 63, wave = threadIdx.x >> 6;
  const int m = lane & 15, quad = lane >> 4;
  const int node_base = (blockIdx.x * 4 + wave) * 16;
  if (node_base >= NN) return;
  const int row = node_base + m;
  frag8 bx[4], bh[4];
#pragma unroll
  for (int kb = 0; kb < 4; ++kb) {
    bx[kb] = *(const frag8*)(x16 + (size_t)row * 128 + kb * 32 + quad * 8);
    bh[kb] = *(const frag8*)(hN + (size_t)row * 128 + kb * 32 + quad * 8);
  }
#pragma unroll
  for (int tj = 0; tj < 8; ++tj) {
    float4 bv = *(const float4*)(bneigh + tj * 16 + quad * 4);
    facc4 acc = {bv.x, bv.y, bv.z, bv.w};
#pragma unroll
    for (int kb = 0; kb < 4; ++kb) {
      acc = mfma16(Wsp[(tj * 4 + kb) * 64 + lane], bx[kb], acc);
      acc = mfma16(Wnp[(tj * 4 + kb) * 64 + lane], bh[kb], acc);
    }
#pragma unroll
    for (int r = 0; r < 4; ++r) acc[r] = fmaxf(acc[r], 0.f);
    uint2 st;
    st.x = (unsigned)f2bf(acc[0]) | ((unsigned)f2bf(acc[1]) << 16);
    st.y = (unsigned)f2bf(acc[2]) | ((unsigned)f2bf(acc[3]) << 16);
    *(uint2*)(h1 + (size_t)row * 128 + tj * 16 + quad * 4) = st;
  }
}

__device__ __forceinline__ float dot2(unsigned a, unsigned b) {
  return bflo(a) * bflo(b) + bfhi(a) * bfhi(b);
}

// out[n] = sigmoid(h1[n].Wself2 + hN2[n].Wneigh2 + b), fp32 out
__global__ __launch_bounds__(256) void out2_kernel(
    const u16* __restrict__ h1, const u16* __restrict__ hN2,
    const u16* __restrict__ ws2, const u16* __restrict__ wn2,
    const float* __restrict__ b2, float* __restrict__ outp)
{
  int n = blockIdx.x * 256 + threadIdx.x;
  if (n >= NN) return;
  const uint4* r1 = (const uint4*)(h1 + (size_t)n * 128);
  const uint4* r2 = (const uint4*)(hN2 + (size_t)n * 128);
  const uint4* w1 = (const uint4*)ws2;
  const uint4* w2 = (const uint4*)wn2;
  float acc = b2[0];
#pragma unroll
  for (int q = 0; q < 16; ++q) {   // 16 uint4 = 128 features
    uint4 a = r1[q], w = w1[q];
    acc += dot2(a.x, w.x) + dot2(a.y, w.y) + dot2(a.z, w.z) + dot2(a.w, w.w);
    uint4 c = r2[q], v = w2[q];
    acc += dot2(c.x, v.x) + dot2(c.y, v.y) + dot2(c.z, v.z) + dot2(c.w, v.w);
  }
  outp[n] = __builtin_amdgcn_rcpf(1.f + __builtin_amdgcn_exp2f(-acc * L2E));
}

extern "C" void kernel_launch(void* const* d_in, const int* in_sizes, int n_in,
                              void* d_out, int out_size, void* d_ws, size_t ws_size,
                              hipStream_t stream) {
  const float* x       = (const float*)d_in[0];
  const int*   nbr     = (const int*)d_in[1];
  const float* Wih1    = (const float*)d_in[2];
  const float* Whh1    = (const float*)d_in[3];
  const float* bih1    = (const float*)d_in[4];
  const float* bhh1    = (const float*)d_in[5];
  const float* Wself1  = (const float*)d_in[6];
  const float* Wneigh1 = (const float*)d_in[7];
  const float* bneigh1 = (const float*)d_in[8];
  const float* Wih2    = (const float*)d_in[9];
  const float* Whh2    = (const float*)d_in[10];
  const float* bih2    = (const float*)d_in[11];
  const float* bhh2    = (const float*)d_in[12];
  const float* Wself2  = (const float*)d_in[13];
  const float* Wneigh2 = (const float*)d_in[14];
  const float* bneigh2 = (const float*)d_in[15];

  char* ws = (char*)d_ws;
  u16*   x16   = (u16*)(ws + OFF_X16);
  u16*   h1    = (u16*)(ws + OFF_H1);
  u16*   hN    = (u16*)(ws + OFF_HN);
  u16*   Xpre  = (u16*)(ws + OFF_XPRE);
  frag8* Wih1p = (frag8*)(ws + OFF_WIH1P);
  frag8* Whh1p = (frag8*)(ws + OFF_WHH1P);
  frag8* Wih2p = (frag8*)(ws + OFF_WIH2P);
  frag8* Whh2p = (frag8*)(ws + OFF_WHH2P);
  frag8* Ws1p  = (frag8*)(ws + OFF_WS1P);
  frag8* Wn1p  = (frag8*)(ws + OFF_WN1P);
  u16*   Ws2b  = (u16*)(ws + OFF_WS2B);
  u16*   Wn2b  = (u16*)(ws + OFF_WN2B);
  float* b1    = (float*)(ws + OFF_B1);
  float* b2    = (float*)(ws + OFF_B2);

  pack_kernel<<<11157, 256, 0, stream>>>(x, Wih1, Whh1, bih1, bhh1, Wself1,
                                         Wneigh1, Wih2, Whh2, bih2, bhh2,
                                         Wself2, Wneigh2, ws);
  // layer 1
  xpre_kernel<<<313, 256, 0, stream>>>(x16, Wih1p, b1, Xpre);
  lstm_kernel<<<1250, 512, 0, stream>>>(Xpre, Whh1p, nbr, hN);
  out1_kernel<<<313, 256, 0, stream>>>(x16, hN, Ws1p, Wn1p, bneigh1, h1);
  // layer 2
  xpre_kernel<<<313, 256, 0, stream>>>(h1, Wih2p, b2, Xpre);
  lstm_kernel<<<1250, 512, 0, stream>>>(Xpre, Whh2p, nbr, hN);
  out2_kernel<<<79, 256, 0, stream>>>(h1, hN, Ws2b, Wn2b, bneigh2, (float*)d_out);
}

// Round 4
// 263.615 us; speedup vs baseline: 4.8197x; 1.1822x over previous
//
#include <hip/hip_runtime.h>

// ---------------------------------------------------------------------------
// SAGE-LSTM on MI355X.
// Xpre = x@Wih^T + b precomputed per layer (hoists the input GEMM out of the
// 16-step recurrence). LSTM: gates^T = Whh.h^T with MFMA 16x16x32 bf16.
//
// R2: fp16 Xpre + gather layout + 1-step register prefetch (565 -> 117 us).
// R3: pair-split 10 waves/block (117 -> 94 us).
// R4: Whh in registers (A = 16 frag8, lives in AGPRs), 8 waves per group,
//     h double-buffered in LDS, one barrier/step (94 -> 77 us). True reg
//     footprint ~124 (60 VGPR + 64 AGPR) -> 16 waves/CU cap; occupancy 36%
//     is that cap minus ramp/drain. lstm is VALU-bound (60% busy, trans-
//     cendental heavy) -> only op-trims left there.
// R5: the scatter-write tax. xpre/out1 stored isolated 8 B chunks per lane
//     (up to 8x HBM write amplification at 64 B burst granularity) -> stage
//     block outputs in LDS, then copy out linearly with coalesced dwordx4.
//     lstm: h->bf16 pack via v_cvt_pk_bf16_f32 (2 ops, RNE) instead of
//     ~20-op manual RNE.
// ---------------------------------------------------------------------------

#define NN   20000
#define L2E  1.4426950408889634f

typedef unsigned short u16;
typedef __attribute__((ext_vector_type(8))) short frag8;     // 8 x bf16
typedef __attribute__((ext_vector_type(4))) float facc4;     // 4 x f32 acc
typedef __attribute__((ext_vector_type(8))) _Float16 half8;  // 8 x fp16

// ---- workspace layout (bytes) ----
#define OFF_X16   0u
#define OFF_H1    5120000u
#define OFF_HN    10240000u
#define OFF_WIH1P 15360000u
#define OFF_WHH1P 15491072u
#define OFF_WIH2P 15622144u
#define OFF_WHH2P 15753216u
#define OFF_WS1P  15884288u
#define OFF_WN1P  15917056u
#define OFF_WS2B  15949824u
#define OFF_WN2B  15950080u
#define OFF_B1    15950336u
#define OFF_B2    15952384u
#define OFF_XPRE  15954432u   // fp16 [NN,512] = 20,480,000 B

__device__ __forceinline__ u16 f2bf(float f) {
  union { float f; unsigned u; } v; v.f = f;
  unsigned r = (v.u + 0x7fffu + ((v.u >> 16) & 1u)) >> 16;  // RNE
  return (u16)r;
}
__device__ __forceinline__ float bflo(unsigned u) {
  union { unsigned u; float f; } v; v.u = u << 16; return v.f;
}
__device__ __forceinline__ float bfhi(unsigned u) {
  union { unsigned u; float f; } v; v.u = u & 0xffff0000u; return v.f;
}
__device__ __forceinline__ unsigned pk2h(float a, float b) {
  union { _Float16 h[2]; unsigned u; } v;
  v.h[0] = (_Float16)a; v.h[1] = (_Float16)b;
  return v.u;
}
// RNE f32x2 -> packed bf16x2 in one HW op (no builtin on gfx950 -> asm)
__device__ __forceinline__ unsigned pkbf(float a, float b) {
  unsigned r;
  asm("v_cvt_pk_bf16_f32 %0, %1, %2" : "=v"(r) : "v"(a), "v"(b));
  return r;
}
__device__ __forceinline__ facc4 mfma16(frag8 a, frag8 b, facc4 c) {
  return __builtin_amdgcn_mfma_f32_16x16x32_bf16(a, b, c, 0, 0, 0);
}
// x prescaled by L2E: sigmoid(x) = 1/(1+2^-xp)
__device__ __forceinline__ float sigm_ps(float xp) {
  return __builtin_amdgcn_rcpf(1.f + __builtin_amdgcn_exp2f(-xp));
}
// x prescaled by 2*L2E: tanh(x) = 1 - 2/(1+2^xp)
__device__ __forceinline__ float tanh_ps(float xp) {
  return 1.f - 2.f * __builtin_amdgcn_rcpf(1.f + __builtin_amdgcn_exp2f(xp));
}
__device__ __forceinline__ float gate_scale(int row) {
  return (row >= 256 && row < 384) ? 2.f * L2E : L2E;  // g-gate rows get 2*log2e
}

// pack [R,128] fp32 row-major -> A-fragment order: dst[i] where
// i = ((tj*4+kb)*64 + lane)*8 + e ; A[row = tj*16+(lane&15)][k = kb*32+(lane>>4)*8+e]
__device__ __forceinline__ void pack512(u16* dst, const float* src, int i) {
  int e = i & 7, ln = (i >> 3) & 63, kb = (i >> 9) & 3, tj = i >> 11;
  int row = tj * 16 + (ln & 15);
  int col = kb * 32 + (ln >> 4) * 8 + e;
  dst[i] = f2bf(src[row * 128 + col] * gate_scale(row));
}
__device__ __forceinline__ void pack128(u16* dst, const float* src, int i) {
  int e = i & 7, ln = (i >> 3) & 63, kb = (i >> 9) & 3, tj = i >> 11;
  dst[i] = f2bf(src[(tj * 16 + (ln & 15)) * 128 + kb * 32 + (ln >> 4) * 8 + e]);
}

__global__ __launch_bounds__(256) void pack_kernel(
    const float* __restrict__ x,
    const float* __restrict__ Wih1, const float* __restrict__ Whh1,
    const float* __restrict__ bih1, const float* __restrict__ bhh1,
    const float* __restrict__ Wself1, const float* __restrict__ Wneigh1,
    const float* __restrict__ Wih2, const float* __restrict__ Whh2,
    const float* __restrict__ bih2, const float* __restrict__ bhh2,
    const float* __restrict__ Wself2, const float* __restrict__ Wneigh2,
    char* __restrict__ ws)
{
  int i = blockIdx.x * 256 + threadIdx.x;
  if (i < 2560000) { ((u16*)(ws + OFF_X16))[i] = f2bf(x[i]); return; }
  i -= 2560000;
  if (i < 65536) { pack512((u16*)(ws + OFF_WIH1P), Wih1, i); return; }
  i -= 65536;
  if (i < 65536) { pack512((u16*)(ws + OFF_WHH1P), Whh1, i); return; }
  i -= 65536;
  if (i < 65536) { pack512((u16*)(ws + OFF_WIH2P), Wih2, i); return; }
  i -= 65536;
  if (i < 65536) { pack512((u16*)(ws + OFF_WHH2P), Whh2, i); return; }
  i -= 65536;
  if (i < 16384) { pack128((u16*)(ws + OFF_WS1P), Wself1, i); return; }
  i -= 16384;
  if (i < 16384) { pack128((u16*)(ws + OFF_WN1P), Wneigh1, i); return; }
  i -= 16384;
  if (i < 128) { ((u16*)(ws + OFF_WS2B))[i] = f2bf(Wself2[i]); return; }
  i -= 128;
  if (i < 128) { ((u16*)(ws + OFF_WN2B))[i] = f2bf(Wneigh2[i]); return; }
  i -= 128;
  if (i < 512) { ((float*)(ws + OFF_B1))[i] = (bih1[i] + bhh1[i]) * gate_scale(i); return; }
  i -= 512;
  if (i < 512) { ((float*)(ws + OFF_B2))[i] = (bih2[i] + bhh2[i]) * gate_scale(i); }
}

// Xpre[n] = inp[n] @ W^T + bias, stored fp16 in gather-friendly layout:
// element offset = n*512 + kt*64 + quad*16 + gate*4 + r
// R5: per-lane 8 B outputs scatter -> stage in LDS, copy out coalesced.
__global__ __launch_bounds__(256) void xpre_kernel(
    const u16* __restrict__ inp,    // [NN,128] bf16
    const frag8* __restrict__ Wp,   // 8192 frags
    const float* __restrict__ bias, // [512] fp32 prescaled
    u16* __restrict__ outp)         // [NN,512] fp16 packed
{
  __shared__ __align__(16) u16 stage[64][512];       // 64 KB
  const int tid = threadIdx.x;
  const int lane = tid & 63, wave = tid >> 6;
  const int m = lane & 15, quad = lane >> 4;
  const int row = blockIdx.x * 64 + wave * 16 + m;
  if (row < NN) {
    frag8 bfr[4];
#pragma unroll
    for (int kb = 0; kb < 4; ++kb)
      bfr[kb] = *(const frag8*)(inp + (size_t)row * 128 + kb * 32 + quad * 8);
    u16* srow = stage[wave * 16 + m];
#pragma unroll
    for (int tj = 0; tj < 32; ++tj) {
      float4 bv = *(const float4*)(bias + tj * 16 + quad * 4);
      facc4 acc = {bv.x, bv.y, bv.z, bv.w};
#pragma unroll
      for (int kb = 0; kb < 4; ++kb)
        acc = mfma16(Wp[(tj * 4 + kb) * 64 + lane], bfr[kb], acc);
      uint2 st = { pk2h(acc[0], acc[1]), pk2h(acc[2], acc[3]) };
      *(uint2*)(srow + (tj & 7) * 64 + quad * 16 + (tj >> 3) * 4) = st;
    }
  }
  __syncthreads();
  const int base = blockIdx.x * 64;
#pragma unroll
  for (int i = tid; i < 4096; i += 256) {            // 64 rows x 64 uint4
    int r = i >> 6, cc = i & 63;
    int n = base + r;
    if (n < NN)
      ((uint4*)(outp + (size_t)n * 512))[cc] = ((const uint4*)stage[r])[cc];
  }
}

// 16-step LSTM over gathered neighbor sequences; final h -> hN (bf16).
// 8 waves per 16-node group; wave g owns kt-tile g (units 16g..16g+15) for
// all 4 gates. Whh A-fragments live in registers (AGPRs).
// h double-buffered in LDS -> one barrier per step.
__global__ __launch_bounds__(512, 4) void lstm_kernel(
    const u16* __restrict__ Xpre,   // [NN,512] fp16 packed, prescaled, bias folded
    const frag8* __restrict__ Wp,   // packed Whh, 8192 frags
    const int* __restrict__ nbr,    // [NN,16]
    u16* __restrict__ hN)           // [NN,128] bf16
{
  __shared__ __align__(16) u16 h_lds[2][16 * 136];   // 8704 B double-buffered h
  const int tid = threadIdx.x;
  const int lane = tid & 63, g = tid >> 6;          // wave g owns kt = g
  const int m = lane & 15, quad = lane >> 4;

  // A-fragments for kt=g: [gate][kb], resident for all 16 steps.
  frag8 A[4][4];
#pragma unroll
  for (int gate = 0; gate < 4; ++gate)
#pragma unroll
    for (int kb = 0; kb < 4; ++kb)
      A[gate][kb] = Wp[((gate * 8 + g) * 4 + kb) * 64 + lane];

  for (int i = tid; i < 16 * 136; i += 512) h_lds[0][i] = 0;

  const int node_base = blockIdx.x * 16;             // 1250*16 == 20000 exact
  // lane holds nbr[node_base + m][quad*4 + s], s=0..3
  int4 idx4 = *(const int4*)(nbr + (size_t)(node_base + m) * 16 + quad * 4);

  facc4 c = {0.f, 0.f, 0.f, 0.f};

  // this lane's 32-byte Xpre slice (kt=g, quad) of neighbor at step t
  auto xslice = [&](int t) -> const uint4* {
    const int tq = t >> 2, ts = t & 3;
    int sel = (ts == 0) ? idx4.x : (ts == 1) ? idx4.y : (ts == 2) ? idx4.z : idx4.w;
    int idx = __shfl(sel, m + (tq << 4), 64);        // neighbor of node m at step t
    return (const uint4*)(Xpre + (size_t)idx * 512) + g * 8 + quad * 2;
  };

  uint4 pX0, pX1;                                    // 1-step-ahead prefetch
  { const uint4* p0 = xslice(0); pX0 = p0[0]; pX1 = p0[1]; }

  __syncthreads();                                   // h zeros + everyone ready

#pragma unroll 1
  for (int t = 0; t < 16; ++t) {
    const u16* hr = h_lds[t & 1];
    u16* hw = h_lds[(t + 1) & 1];
    const uint4* pn = xslice(t < 15 ? t + 1 : 15);   // t=15 re-read is an L2 hit

    frag8 bfr[4];                                    // B = full h (prev step)
#pragma unroll
    for (int kb = 0; kb < 4; ++kb)
      bfr[kb] = *(const frag8*)(hr + m * 136 + kb * 32 + quad * 8);

    union { uint4 u; half8 h; } ua, ub;
    ua.u = pX0; ub.u = pX1;
    facc4 ai = {(float)ua.h[0], (float)ua.h[1], (float)ua.h[2], (float)ua.h[3]};
    facc4 af = {(float)ua.h[4], (float)ua.h[5], (float)ua.h[6], (float)ua.h[7]};
    facc4 ag = {(float)ub.h[0], (float)ub.h[1], (float)ub.h[2], (float)ub.h[3]};
    facc4 ao = {(float)ub.h[4], (float)ub.h[5], (float)ub.h[6], (float)ub.h[7]};
    // refill prefetch: a full step of MFMA+VALU to hide under
    pX0 = pn[0]; pX1 = pn[1];

#pragma unroll
    for (int kb = 0; kb < 4; ++kb) {
      ai = mfma16(A[0][kb], bfr[kb], ai);
      af = mfma16(A[1][kb], bfr[kb], af);
      ag = mfma16(A[2][kb], bfr[kb], ag);
      ao = mfma16(A[3][kb], bfr[kb], ao);
    }

    facc4 hv;
#pragma unroll
    for (int r = 0; r < 4; ++r) {
      float si = sigm_ps(ai[r]);
      float sf = sigm_ps(af[r]);
      float tg = tanh_ps(ag[r]);
      float cn = sf * c[r] + si * tg;
      c[r] = cn;
      float so = sigm_ps(ao[r]);
      hv[r] = so * tanh_ps((2.f * L2E) * cn);
    }
    uint2 hp = { pkbf(hv[0], hv[1]), pkbf(hv[2], hv[3]) };

    if (t < 15) {
      *(uint2*)(hw + m * 136 + g * 16 + quad * 4) = hp;
      // LDS-only drain: prefetch vmcnt loads stay in flight across barrier
      asm volatile("s_waitcnt lgkmcnt(0)" ::: "memory");
      __builtin_amdgcn_s_barrier();
    } else {
      *(uint2*)(hN + (size_t)(node_base + m) * 128 + g * 16 + quad * 4) = hp;
    }
  }
}

// h1 = relu(x@Wself^T + hN@Wneigh^T + bneigh), bf16 out. 8 j-tiles.
// R5: LDS-staged coalesced output.
__global__ __launch_bounds__(256) void out1_kernel(
    const u16* __restrict__ x16, const u16* __restrict__ hN,
    const frag8* __restrict__ Wsp, const frag8* __restrict__ Wnp,
    const float* __restrict__ bneigh, u16* __restrict__ h1)
{
  __shared__ __align__(16) u16 stage[64][128];       // 16 KB
  const int tid = threadIdx.x;
  const int lane = tid & 63, wave = tid >> 6;
  const int m = lane & 15, quad = lane >> 4;
  const int row = blockIdx.x * 64 + wave * 16 + m;
  if (row < NN) {
    frag8 bx[4], bh[4];
#pragma unroll
    for (int kb = 0; kb < 4; ++kb) {
      bx[kb] = *(const frag8*)(x16 + (size_t)row * 128 + kb * 32 + quad * 8);
      bh[kb] = *(const frag8*)(hN + (size_t)row * 128 + kb * 32 + quad * 8);
    }
    u16* srow = stage[wave * 16 + m];
#pragma unroll
    for (int tj = 0; tj < 8; ++tj) {
      float4 bv = *(const float4*)(bneigh + tj * 16 + quad * 4);
      facc4 acc = {bv.x, bv.y, bv.z, bv.w};
#pragma unroll
      for (int kb = 0; kb < 4; ++kb) {
        acc = mfma16(Wsp[(tj * 4 + kb) * 64 + lane], bx[kb], acc);
        acc = mfma16(Wnp[(tj * 4 + kb) * 64 + lane], bh[kb], acc);
      }
      uint2 st = { pkbf(fmaxf(acc[0], 0.f), fmaxf(acc[1], 0.f)),
                   pkbf(fmaxf(acc[2], 0.f), fmaxf(acc[3], 0.f)) };
      *(uint2*)(srow + tj * 16 + quad * 4) = st;
    }
  }
  __syncthreads();
  const int base = blockIdx.x * 64;
#pragma unroll
  for (int i = tid; i < 1024; i += 256) {            // 64 rows x 16 uint4
    int r = i >> 4, cc = i & 15;
    int n = base + r;
    if (n < NN)
      ((uint4*)(h1 + (size_t)n * 128))[cc] = ((const uint4*)stage[r])[cc];
  }
}

__device__ __forceinline__ float dot2(unsigned a, unsigned b) {
  return bflo(a) * bflo(b) + bfhi(a) * bfhi(b);
}

// out[n] = sigmoid(h1[n].Wself2 + hN2[n].Wneigh2 + b), fp32 out
__global__ __launch_bounds__(256) void out2_kernel(
    const u16* __restrict__ h1, const u16* __restrict__ hN2,
    const u16* __restrict__ ws2, const u16* __restrict__ wn2,
    const float* __restrict__ b2, float* __restrict__ outp)
{
  int n = blockIdx.x * 256 + threadIdx.x;
  if (n >= NN) return;
  const uint4* r1 = (const uint4*)(h1 + (size_t)n * 128);
  const uint4* r2 = (const uint4*)(hN2 + (size_t)n * 128);
  const uint4* w1 = (const uint4*)ws2;
  const uint4* w2 = (const uint4*)wn2;
  float acc = b2[0];
#pragma unroll
  for (int q = 0; q < 16; ++q) {   // 16 uint4 = 128 features
    uint4 a = r1[q], w = w1[q];
    acc += dot2(a.x, w.x) + dot2(a.y, w.y) + dot2(a.z, w.z) + dot2(a.w, w.w);
    uint4 c = r2[q], v = w2[q];
    acc += dot2(c.x, v.x) + dot2(c.y, v.y) + dot2(c.z, v.z) + dot2(c.w, v.w);
  }
  outp[n] = __builtin_amdgcn_rcpf(1.f + __builtin_amdgcn_exp2f(-acc * L2E));
}

extern "C" void kernel_launch(void* const* d_in, const int* in_sizes, int n_in,
                              void* d_out, int out_size, void* d_ws, size_t ws_size,
                              hipStream_t stream) {
  const float* x       = (const float*)d_in[0];
  const int*   nbr     = (const int*)d_in[1];
  const float* Wih1    = (const float*)d_in[2];
  const float* Whh1    = (const float*)d_in[3];
  const float* bih1    = (const float*)d_in[4];
  const float* bhh1    = (const float*)d_in[5];
  const float* Wself1  = (const float*)d_in[6];
  const float* Wneigh1 = (const float*)d_in[7];
  const float* bneigh1 = (const float*)d_in[8];
  const float* Wih2    = (const float*)d_in[9];
  const float* Whh2    = (const float*)d_in[10];
  const float* bih2    = (const float*)d_in[11];
  const float* bhh2    = (const float*)d_in[12];
  const float* Wself2  = (const float*)d_in[13];
  const float* Wneigh2 = (const float*)d_in[14];
  const float* bneigh2 = (const float*)d_in[15];

  char* ws = (char*)d_ws;
  u16*   x16   = (u16*)(ws + OFF_X16);
  u16*   h1    = (u16*)(ws + OFF_H1);
  u16*   hN    = (u16*)(ws + OFF_HN);
  u16*   Xpre  = (u16*)(ws + OFF_XPRE);
  frag8* Wih1p = (frag8*)(ws + OFF_WIH1P);
  frag8* Whh1p = (frag8*)(ws + OFF_WHH1P);
  frag8* Wih2p = (frag8*)(ws + OFF_WIH2P);
  frag8* Whh2p = (frag8*)(ws + OFF_WHH2P);
  frag8* Ws1p  = (frag8*)(ws + OFF_WS1P);
  frag8* Wn1p  = (frag8*)(ws + OFF_WN1P);
  u16*   Ws2b  = (u16*)(ws + OFF_WS2B);
  u16*   Wn2b  = (u16*)(ws + OFF_WN2B);
  float* b1    = (float*)(ws + OFF_B1);
  float* b2    = (float*)(ws + OFF_B2);

  pack_kernel<<<11157, 256, 0, stream>>>(x, Wih1, Whh1, bih1, bhh1, Wself1,
                                         Wneigh1, Wih2, Whh2, bih2, bhh2,
                                         Wself2, Wneigh2, ws);
  // layer 1
  xpre_kernel<<<313, 256, 0, stream>>>(x16, Wih1p, b1, Xpre);
  lstm_kernel<<<1250, 512, 0, stream>>>(Xpre, Whh1p, nbr, hN);
  out1_kernel<<<313, 256, 0, stream>>>(x16, hN, Ws1p, Wn1p, bneigh1, h1);
  // layer 2
  xpre_kernel<<<313, 256, 0, stream>>>(h1, Wih2p, b2, Xpre);
  lstm_kernel<<<1250, 512, 0, stream>>>(Xpre, Whh2p, nbr, hN);
  out2_kernel<<<79, 256, 0, stream>>>(h1, hN, Ws2b, Wn2b, bneigh2, (float*)d_out);
}

// Round 5
// 258.217 us; speedup vs baseline: 4.9204x; 1.0209x over previous
//
#include <hip/hip_runtime.h>

// ---------------------------------------------------------------------------
// SAGE-LSTM on MI355X.
// Xpre = x@Wih^T + b precomputed per layer (hoists the input GEMM out of the
// 16-step recurrence). LSTM: gates^T = Whh.h^T with MFMA 16x16x32 bf16.
//
// R2: fp16 Xpre + gather layout + 1-step register prefetch (565 -> 117 us).
// R3: pair-split 10 waves/block (117 -> 94 us).
// R4: Whh in registers (AGPRs), 8 waves/group, h double-buffered in LDS,
//     one barrier/step (94 -> 77 us). lstm is VALU/trans-bound now.
// R5: scatter-write tax: LDS-stage xpre/out1 outputs, coalesced dwordx4
//     copy-out; v_cvt_pk_bf16_f32 for h packing (263.6 us total).
// R6: small-kernel consolidation. others=115us vs ~20us BW floor:
//     - out1 fused into lstm1 epilogue (h already in LDS; wave g does
//       j-tile g; stage + coalesced copy to h1). hN global round-trip gone.
//     - out2 fused into lstm2 epilogue (32 threads/node dot+shfl reduce).
//     - xpre: 8 waves/block, j-split (2.45 waves/SIMD, half serial chain).
//     - pack: float4 + cvt_pk vectorized x->bf16.
//     7 kernels -> 5.
// ---------------------------------------------------------------------------

#define NN   20000
#define L2E  1.4426950408889634f

typedef unsigned short u16;
typedef __attribute__((ext_vector_type(8))) short frag8;     // 8 x bf16
typedef __attribute__((ext_vector_type(4))) float facc4;     // 4 x f32 acc
typedef __attribute__((ext_vector_type(8))) _Float16 half8;  // 8 x fp16

// ---- workspace layout (bytes) ----
#define OFF_X16   0u
#define OFF_H1    5120000u
#define OFF_WIH1P 15360000u
#define OFF_WHH1P 15491072u
#define OFF_WIH2P 15622144u
#define OFF_WHH2P 15753216u
#define OFF_WS1P  15884288u
#define OFF_WN1P  15917056u
#define OFF_WS2B  15949824u
#define OFF_WN2B  15950080u
#define OFF_B1    15950336u
#define OFF_B2    15952384u
#define OFF_XPRE  15954432u   // fp16 [NN,512] = 20,480,000 B

__device__ __forceinline__ u16 f2bf(float f) {
  union { float f; unsigned u; } v; v.f = f;
  unsigned r = (v.u + 0x7fffu + ((v.u >> 16) & 1u)) >> 16;  // RNE
  return (u16)r;
}
__device__ __forceinline__ float bflo(unsigned u) {
  union { unsigned u; float f; } v; v.u = u << 16; return v.f;
}
__device__ __forceinline__ float bfhi(unsigned u) {
  union { unsigned u; float f; } v; v.u = u & 0xffff0000u; return v.f;
}
__device__ __forceinline__ unsigned pk2h(float a, float b) {
  union { _Float16 h[2]; unsigned u; } v;
  v.h[0] = (_Float16)a; v.h[1] = (_Float16)b;
  return v.u;
}
// RNE f32x2 -> packed bf16x2 in one HW op (no builtin on gfx950 -> asm)
__device__ __forceinline__ unsigned pkbf(float a, float b) {
  unsigned r;
  asm("v_cvt_pk_bf16_f32 %0, %1, %2" : "=v"(r) : "v"(a), "v"(b));
  return r;
}
__device__ __forceinline__ facc4 mfma16(frag8 a, frag8 b, facc4 c) {
  return __builtin_amdgcn_mfma_f32_16x16x32_bf16(a, b, c, 0, 0, 0);
}
// x prescaled by L2E: sigmoid(x) = 1/(1+2^-xp)
__device__ __forceinline__ float sigm_ps(float xp) {
  return __builtin_amdgcn_rcpf(1.f + __builtin_amdgcn_exp2f(-xp));
}
// x prescaled by 2*L2E: tanh(x) = 1 - 2/(1+2^xp)
__device__ __forceinline__ float tanh_ps(float xp) {
  return 1.f - 2.f * __builtin_amdgcn_rcpf(1.f + __builtin_amdgcn_exp2f(xp));
}
__device__ __forceinline__ float gate_scale(int row) {
  return (row >= 256 && row < 384) ? 2.f * L2E : L2E;  // g-gate rows get 2*log2e
}
__device__ __forceinline__ float dot2(unsigned a, unsigned b) {
  return bflo(a) * bflo(b) + bfhi(a) * bfhi(b);
}

// pack [R,128] fp32 row-major -> A-fragment order: dst[i] where
// i = ((tj*4+kb)*64 + lane)*8 + e ; A[row = tj*16+(lane&15)][k = kb*32+(lane>>4)*8+e]
__device__ __forceinline__ void pack512(u16* dst, const float* src, int i) {
  int e = i & 7, ln = (i >> 3) & 63, kb = (i >> 9) & 3, tj = i >> 11;
  int row = tj * 16 + (ln & 15);
  int col = kb * 32 + (ln >> 4) * 8 + e;
  dst[i] = f2bf(src[row * 128 + col] * gate_scale(row));
}
__device__ __forceinline__ void pack128(u16* dst, const float* src, int i) {
  int e = i & 7, ln = (i >> 3) & 63, kb = (i >> 9) & 3, tj = i >> 11;
  dst[i] = f2bf(src[(tj * 16 + (ln & 15)) * 128 + kb * 32 + (ln >> 4) * 8 + e]);
}

__global__ __launch_bounds__(256) void pack_kernel(
    const float* __restrict__ x,
    const float* __restrict__ Wih1, const float* __restrict__ Whh1,
    const float* __restrict__ bih1, const float* __restrict__ bhh1,
    const float* __restrict__ Wself1, const float* __restrict__ Wneigh1,
    const float* __restrict__ Wih2, const float* __restrict__ Whh2,
    const float* __restrict__ bih2, const float* __restrict__ bhh2,
    const float* __restrict__ Wself2, const float* __restrict__ Wneigh2,
    char* __restrict__ ws)
{
  int i = blockIdx.x * 256 + threadIdx.x;
  if (i < 640000) {                                   // x -> bf16, 4 elems/thread
    float4 v = ((const float4*)x)[i];
    uint2 st = { pkbf(v.x, v.y), pkbf(v.z, v.w) };
    ((uint2*)(ws + OFF_X16))[i] = st;
    return;
  }
  i -= 640000;
  if (i < 65536) { pack512((u16*)(ws + OFF_WIH1P), Wih1, i); return; }
  i -= 65536;
  if (i < 65536) { pack512((u16*)(ws + OFF_WHH1P), Whh1, i); return; }
  i -= 65536;
  if (i < 65536) { pack512((u16*)(ws + OFF_WIH2P), Wih2, i); return; }
  i -= 65536;
  if (i < 65536) { pack512((u16*)(ws + OFF_WHH2P), Whh2, i); return; }
  i -= 65536;
  if (i < 16384) { pack128((u16*)(ws + OFF_WS1P), Wself1, i); return; }
  i -= 16384;
  if (i < 16384) { pack128((u16*)(ws + OFF_WN1P), Wneigh1, i); return; }
  i -= 16384;
  if (i < 128) { ((u16*)(ws + OFF_WS2B))[i] = f2bf(Wself2[i]); return; }
  i -= 128;
  if (i < 128) { ((u16*)(ws + OFF_WN2B))[i] = f2bf(Wneigh2[i]); return; }
  i -= 128;
  if (i < 512) { ((float*)(ws + OFF_B1))[i] = (bih1[i] + bhh1[i]) * gate_scale(i); return; }
  i -= 512;
  if (i < 512) { ((float*)(ws + OFF_B2))[i] = (bih2[i] + bhh2[i]) * gate_scale(i); }
}

// Xpre[n] = inp[n] @ W^T + bias, stored fp16 in gather-friendly layout:
// element offset = n*512 + kt*64 + quad*16 + gate*4 + r
// R6: 8 waves/block, wave g = rows (g&3)*16.., tj half g>>2 (16 tj each).
__global__ __launch_bounds__(512) void xpre_kernel(
    const u16* __restrict__ inp,    // [NN,128] bf16
    const frag8* __restrict__ Wp,   // 8192 frags
    const float* __restrict__ bias, // [512] fp32 prescaled
    u16* __restrict__ outp)         // [NN,512] fp16 packed
{
  __shared__ __align__(16) u16 stage[64][512];       // 64 KB
  const int tid = threadIdx.x;
  const int lane = tid & 63, wave = tid >> 6;
  const int m = lane & 15, quad = lane >> 4;
  const int rg = wave & 3, jh = wave >> 2;           // row-group, j-half
  const int row = blockIdx.x * 64 + rg * 16 + m;
  if (row < NN) {
    frag8 bfr[4];
#pragma unroll
    for (int kb = 0; kb < 4; ++kb)
      bfr[kb] = *(const frag8*)(inp + (size_t)row * 128 + kb * 32 + quad * 8);
    u16* srow = stage[rg * 16 + m];
#pragma unroll
    for (int j = 0; j < 16; ++j) {
      const int tj = jh * 16 + j;
      float4 bv = *(const float4*)(bias + tj * 16 + quad * 4);
      facc4 acc = {bv.x, bv.y, bv.z, bv.w};
#pragma unroll
      for (int kb = 0; kb < 4; ++kb)
        acc = mfma16(Wp[(tj * 4 + kb) * 64 + lane], bfr[kb], acc);
      uint2 st = { pk2h(acc[0], acc[1]), pk2h(acc[2], acc[3]) };
      *(uint2*)(srow + (tj & 7) * 64 + quad * 16 + (tj >> 3) * 4) = st;
    }
  }
  __syncthreads();
  const int base = blockIdx.x * 64;
#pragma unroll
  for (int i = tid; i < 4096; i += 512) {            // 64 rows x 64 uint4
    int r = i >> 6, cc = i & 63;
    int n = base + r;
    if (n < NN)
      ((uint4*)(outp + (size_t)n * 512))[cc] = ((const uint4*)stage[r])[cc];
  }
}

// 16-step LSTM over gathered neighbor sequences, fused output layer.
// 8 waves per 16-node group; wave g owns kt-tile g (units 16g..16g+15) for
// all 4 gates; Whh A-fragments in registers (AGPRs); h double-buffered LDS.
// mode 0: epilogue = out1 (h1 = relu(x@Ws^T + h@Wn^T + b)), writes h1.
// mode 1: epilogue = out2 (sigmoid(h1.ws2 + h.wn2 + b)), writes outp.
__global__ __launch_bounds__(512, 4) void lstm_kernel(
    const u16* __restrict__ Xpre,   // [NN,512] fp16 packed, prescaled, bias folded
    const frag8* __restrict__ Wp,   // packed Whh, 8192 frags
    const int* __restrict__ nbr,    // [NN,16]
    const u16* __restrict__ xin,    // mode0: x16 [NN,128] bf16
    const frag8* __restrict__ Wsp, const frag8* __restrict__ Wnp,  // mode0
    const float* __restrict__ bias_o,                              // mode0
    const u16* __restrict__ ws2, const u16* __restrict__ wn2,      // mode1
    const float* __restrict__ b2,                                  // mode1
    u16* __restrict__ h1,           // mode0 out / mode1 in
    float* __restrict__ outp,       // mode1 out
    int mode)
{
  __shared__ __align__(16) u16 h_lds[2][16 * 136];   // 8704 B double-buffered h
  const int tid = threadIdx.x;
  const int lane = tid & 63, g = tid >> 6;          // wave g owns kt = g
  const int m = lane & 15, quad = lane >> 4;

  // A-fragments for kt=g: [gate][kb], resident for all 16 steps.
  frag8 A[4][4];
#pragma unroll
  for (int gate = 0; gate < 4; ++gate)
#pragma unroll
    for (int kb = 0; kb < 4; ++kb)
      A[gate][kb] = Wp[((gate * 8 + g) * 4 + kb) * 64 + lane];

  for (int i = tid; i < 16 * 136; i += 512) h_lds[0][i] = 0;

  const int node_base = blockIdx.x * 16;             // 1250*16 == 20000 exact
  // lane holds nbr[node_base + m][quad*4 + s], s=0..3
  int4 idx4 = *(const int4*)(nbr + (size_t)(node_base + m) * 16 + quad * 4);

  facc4 c = {0.f, 0.f, 0.f, 0.f};

  // this lane's 32-byte Xpre slice (kt=g, quad) of neighbor at step t
  auto xslice = [&](int t) -> const uint4* {
    const int tq = t >> 2, ts = t & 3;
    int sel = (ts == 0) ? idx4.x : (ts == 1) ? idx4.y : (ts == 2) ? idx4.z : idx4.w;
    int idx = __shfl(sel, m + (tq << 4), 64);        // neighbor of node m at step t
    return (const uint4*)(Xpre + (size_t)idx * 512) + g * 8 + quad * 2;
  };

  uint4 pX0, pX1;                                    // 1-step-ahead prefetch
  { const uint4* p0 = xslice(0); pX0 = p0[0]; pX1 = p0[1]; }

  __syncthreads();                                   // h zeros + everyone ready

#pragma unroll 1
  for (int t = 0; t < 16; ++t) {
    const u16* hr = h_lds[t & 1];
    u16* hw = h_lds[(t + 1) & 1];
    const uint4* pn = xslice(t < 15 ? t + 1 : 15);   // t=15 re-read is an L2 hit

    frag8 bfr[4];                                    // B = full h (prev step)
#pragma unroll
    for (int kb = 0; kb < 4; ++kb)
      bfr[kb] = *(const frag8*)(hr + m * 136 + kb * 32 + quad * 8);

    union { uint4 u; half8 h; } ua, ub;
    ua.u = pX0; ub.u = pX1;
    facc4 ai = {(float)ua.h[0], (float)ua.h[1], (float)ua.h[2], (float)ua.h[3]};
    facc4 af = {(float)ua.h[4], (float)ua.h[5], (float)ua.h[6], (float)ua.h[7]};
    facc4 ag = {(float)ub.h[0], (float)ub.h[1], (float)ub.h[2], (float)ub.h[3]};
    facc4 ao = {(float)ub.h[4], (float)ub.h[5], (float)ub.h[6], (float)ub.h[7]};
    // refill prefetch: a full step of MFMA+VALU to hide under
    pX0 = pn[0]; pX1 = pn[1];

#pragma unroll
    for (int kb = 0; kb < 4; ++kb) {
      ai = mfma16(A[0][kb], bfr[kb], ai);
      af = mfma16(A[1][kb], bfr[kb], af);
      ag = mfma16(A[2][kb], bfr[kb], ag);
      ao = mfma16(A[3][kb], bfr[kb], ao);
    }

    facc4 hv;
#pragma unroll
    for (int r = 0; r < 4; ++r) {
      float si = sigm_ps(ai[r]);
      float sf = sigm_ps(af[r]);
      float tg = tanh_ps(ag[r]);
      float cn = sf * c[r] + si * tg;
      c[r] = cn;
      float so = sigm_ps(ao[r]);
      hv[r] = so * tanh_ps((2.f * L2E) * cn);
    }
    uint2 hp = { pkbf(hv[0], hv[1]), pkbf(hv[2], hv[3]) };
    *(uint2*)(hw + m * 136 + g * 16 + quad * 4) = hp;
    // LDS-only drain: prefetch vmcnt loads stay in flight across barrier
    asm volatile("s_waitcnt lgkmcnt(0)" ::: "memory");
    __builtin_amdgcn_s_barrier();
  }

  const u16* hf = h_lds[0];                          // final h (16 steps -> buf 0)

  if (mode == 0) {
    // ---- fused out1: h1 = relu(x@Ws^T + h@Wn^T + b), wave g = j-tile g ----
    const int row = node_base + m;
    frag8 bx[4], bh[4];
#pragma unroll
    for (int kb = 0; kb < 4; ++kb) {
      bx[kb] = *(const frag8*)(xin + (size_t)row * 128 + kb * 32 + quad * 8);
      bh[kb] = *(const frag8*)(hf + m * 136 + kb * 32 + quad * 8);
    }
    float4 bv = *(const float4*)(bias_o + g * 16 + quad * 4);
    facc4 acc = {bv.x, bv.y, bv.z, bv.w};
#pragma unroll
    for (int kb = 0; kb < 4; ++kb) {
      frag8 wsk = Wsp[(g * 4 + kb) * 64 + lane];
      acc = mfma16(wsk, bx[kb], acc);
      frag8 wnk = Wnp[(g * 4 + kb) * 64 + lane];
      acc = mfma16(wnk, bh[kb], acc);
    }
    uint2 st = { pkbf(fmaxf(acc[0], 0.f), fmaxf(acc[1], 0.f)),
                 pkbf(fmaxf(acc[2], 0.f), fmaxf(acc[3], 0.f)) };
    u16* stg = (u16*)h_lds[1];                       // free after final barrier
    *(uint2*)(stg + m * 136 + g * 16 + quad * 4) = st;
    __syncthreads();
    const int r = tid >> 5, cc = tid & 31;           // 16 rows x 32 x 8 B
    *(uint2*)(h1 + (size_t)(node_base + r) * 128 + cc * 4) =
        *(const uint2*)(stg + r * 136 + cc * 4);
  } else {
    // ---- fused out2: sigmoid(h1.ws2 + h.wn2 + b), 32 threads/node ----
    const int n = tid >> 5, cc = tid & 31;
    uint2 a = *(const uint2*)(h1 + (size_t)(node_base + n) * 128 + cc * 4);
    uint2 w = *(const uint2*)(ws2 + cc * 4);
    uint2 b = *(const uint2*)(hf + n * 136 + cc * 4);
    uint2 v = *(const uint2*)(wn2 + cc * 4);
    float p = dot2(a.x, w.x) + dot2(a.y, w.y) + dot2(b.x, v.x) + dot2(b.y, v.y);
#pragma unroll
    for (int s = 1; s < 32; s <<= 1) p += __shfl_xor(p, s, 64);
    if (cc == 0) {
      float acc = p + b2[0];
      outp[node_base + n] =
          __builtin_amdgcn_rcpf(1.f + __builtin_amdgcn_exp2f(-acc * L2E));
    }
  }
}

extern "C" void kernel_launch(void* const* d_in, const int* in_sizes, int n_in,
                              void* d_out, int out_size, void* d_ws, size_t ws_size,
                              hipStream_t stream) {
  const float* x       = (const float*)d_in[0];
  const int*   nbr     = (const int*)d_in[1];
  const float* Wih1    = (const float*)d_in[2];
  const float* Whh1    = (const float*)d_in[3];
  const float* bih1    = (const float*)d_in[4];
  const float* bhh1    = (const float*)d_in[5];
  const float* Wself1  = (const float*)d_in[6];
  const float* Wneigh1 = (const float*)d_in[7];
  const float* bneigh1 = (const float*)d_in[8];
  const float* Wih2    = (const float*)d_in[9];
  const float* Whh2    = (const float*)d_in[10];
  const float* bih2    = (const float*)d_in[11];
  const float* bhh2    = (const float*)d_in[12];
  const float* Wself2  = (const float*)d_in[13];
  const float* Wneigh2 = (const float*)d_in[14];
  const float* bneigh2 = (const float*)d_in[15];

  char* ws = (char*)d_ws;
  u16*   x16   = (u16*)(ws + OFF_X16);
  u16*   h1    = (u16*)(ws + OFF_H1);
  u16*   Xpre  = (u16*)(ws + OFF_XPRE);
  frag8* Wih1p = (frag8*)(ws + OFF_WIH1P);
  frag8* Whh1p = (frag8*)(ws + OFF_WHH1P);
  frag8* Wih2p = (frag8*)(ws + OFF_WIH2P);
  frag8* Whh2p = (frag8*)(ws + OFF_WHH2P);
  frag8* Ws1p  = (frag8*)(ws + OFF_WS1P);
  frag8* Wn1p  = (frag8*)(ws + OFF_WN1P);
  u16*   Ws2b  = (u16*)(ws + OFF_WS2B);
  u16*   Wn2b  = (u16*)(ws + OFF_WN2B);
  float* b1    = (float*)(ws + OFF_B1);
  float* b2    = (float*)(ws + OFF_B2);

  pack_kernel<<<3657, 256, 0, stream>>>(x, Wih1, Whh1, bih1, bhh1, Wself1,
                                        Wneigh1, Wih2, Whh2, bih2, bhh2,
                                        Wself2, Wneigh2, ws);
  // layer 1
  xpre_kernel<<<313, 512, 0, stream>>>(x16, Wih1p, b1, Xpre);
  lstm_kernel<<<1250, 512, 0, stream>>>(Xpre, Whh1p, nbr, x16, Ws1p, Wn1p,
                                        bneigh1, Ws2b, Wn2b, bneigh2, h1,
                                        (float*)d_out, 0);
  // layer 2
  xpre_kernel<<<313, 512, 0, stream>>>(h1, Wih2p, b2, Xpre);
  lstm_kernel<<<1250, 512, 0, stream>>>(Xpre, Whh2p, nbr, x16, Ws1p, Wn1p,
                                        bneigh1, Ws2b, Wn2b, bneigh2, h1,
                                        (float*)d_out, 1);
}

// Round 6
// 245.494 us; speedup vs baseline: 5.1754x; 1.0518x over previous
//
#include <hip/hip_runtime.h>

// ---------------------------------------------------------------------------
// SAGE-LSTM on MI355X.
// Xpre = x@Wih^T + b precomputed per layer (hoists the input GEMM out of the
// 16-step recurrence). LSTM: gates^T = Whh.h^T with MFMA 16x16x32 bf16.
//
// R2: fp16 Xpre + gather layout + 1-step register prefetch (565 -> 117 us).
// R3: pair-split 10 waves/block (117 -> 94 us).
// R4: Whh in registers (AGPRs), 8 waves/group, h double-buffered LDS (77 us).
// R5: LDS-staged coalesced stores; v_cvt_pk_bf16_f32 packing (263 us).
// R6: out1/out2 fused into lstm epilogues; 7 -> 5 kernels (258 us).
// R7: row-locality fusion round.
//     - xpre2 fused into lstm1 epilogue: h1 tile is already in LDS; wave g
//       computes 4 j-tiles of Xpre2 for its 16 nodes. Ping-pong XpreA/XpreB
//       (single buffer would race with other blocks' gathers).
//     - x-cvt + xpre1 fused into prep1 (reads x fp32 once; writes x16+XpreA).
//     - xpre stage LDS stride was 1024 B = 32 banks exactly -> 16-way
//       conflict on gate writes; pad rows to 520 u16 (2-way = free).
//     5 -> 4 kernels; x16/h1 HBM re-read passes eliminated.
// ---------------------------------------------------------------------------

#define NN   20000
#define L2E  1.4426950408889634f

typedef unsigned short u16;
typedef __attribute__((ext_vector_type(8))) short frag8;     // 8 x bf16
typedef __attribute__((ext_vector_type(4))) float facc4;     // 4 x f32 acc
typedef __attribute__((ext_vector_type(8))) _Float16 half8;  // 8 x fp16

// ---- workspace layout (bytes) ----
#define OFF_X16   0u
#define OFF_H1    5120000u
#define OFF_WIH1P 15360000u
#define OFF_WHH1P 15491072u
#define OFF_WIH2P 15622144u
#define OFF_WHH2P 15753216u
#define OFF_WS1P  15884288u
#define OFF_WN1P  15917056u
#define OFF_WS2B  15949824u
#define OFF_WN2B  15950080u
#define OFF_B1    15950336u
#define OFF_B2    15952384u
#define OFF_XPREA 15954432u   // fp16 [NN,512] = 20,480,000 B
#define OFF_XPREB 36434432u   // fp16 [NN,512] = 20,480,000 B (ends 56,914,432)

__device__ __forceinline__ u16 f2bf(float f) {
  union { float f; unsigned u; } v; v.f = f;
  unsigned r = (v.u + 0x7fffu + ((v.u >> 16) & 1u)) >> 16;  // RNE
  return (u16)r;
}
__device__ __forceinline__ float bflo(unsigned u) {
  union { unsigned u; float f; } v; v.u = u << 16; return v.f;
}
__device__ __forceinline__ float bfhi(unsigned u) {
  union { unsigned u; float f; } v; v.u = u & 0xffff0000u; return v.f;
}
__device__ __forceinline__ unsigned pk2h(float a, float b) {
  union { _Float16 h[2]; unsigned u; } v;
  v.h[0] = (_Float16)a; v.h[1] = (_Float16)b;
  return v.u;
}
// RNE f32x2 -> packed bf16x2 in one HW op (no builtin on gfx950 -> asm)
__device__ __forceinline__ unsigned pkbf(float a, float b) {
  unsigned r;
  asm("v_cvt_pk_bf16_f32 %0, %1, %2" : "=v"(r) : "v"(a), "v"(b));
  return r;
}
__device__ __forceinline__ facc4 mfma16(frag8 a, frag8 b, facc4 c) {
  return __builtin_amdgcn_mfma_f32_16x16x32_bf16(a, b, c, 0, 0, 0);
}
// x prescaled by L2E: sigmoid(x) = 1/(1+2^-xp)
__device__ __forceinline__ float sigm_ps(float xp) {
  return __builtin_amdgcn_rcpf(1.f + __builtin_amdgcn_exp2f(-xp));
}
// x prescaled by 2*L2E: tanh(x) = 1 - 2/(1+2^xp)
__device__ __forceinline__ float tanh_ps(float xp) {
  return 1.f - 2.f * __builtin_amdgcn_rcpf(1.f + __builtin_amdgcn_exp2f(xp));
}
__device__ __forceinline__ float gate_scale(int row) {
  return (row >= 256 && row < 384) ? 2.f * L2E : L2E;  // g-gate rows get 2*log2e
}
__device__ __forceinline__ float dot2(unsigned a, unsigned b) {
  return bflo(a) * bflo(b) + bfhi(a) * bfhi(b);
}

// pack [R,128] fp32 row-major -> A-fragment order: dst[i] where
// i = ((tj*4+kb)*64 + lane)*8 + e ; A[row = tj*16+(lane&15)][k = kb*32+(lane>>4)*8+e]
__device__ __forceinline__ void pack512(u16* dst, const float* src, int i) {
  int e = i & 7, ln = (i >> 3) & 63, kb = (i >> 9) & 3, tj = i >> 11;
  int row = tj * 16 + (ln & 15);
  int col = kb * 32 + (ln >> 4) * 8 + e;
  dst[i] = f2bf(src[row * 128 + col] * gate_scale(row));
}
__device__ __forceinline__ void pack128(u16* dst, const float* src, int i) {
  int e = i & 7, ln = (i >> 3) & 63, kb = (i >> 9) & 3, tj = i >> 11;
  dst[i] = f2bf(src[(tj * 16 + (ln & 15)) * 128 + kb * 32 + (ln >> 4) * 8 + e]);
}

// weights + biases only (x handled by prep1). 296,192 threads exact.
__global__ __launch_bounds__(256) void pack_kernel(
    const float* __restrict__ Wih1, const float* __restrict__ Whh1,
    const float* __restrict__ bih1, const float* __restrict__ bhh1,
    const float* __restrict__ Wself1, const float* __restrict__ Wneigh1,
    const float* __restrict__ Wih2, const float* __restrict__ Whh2,
    const float* __restrict__ bih2, const float* __restrict__ bhh2,
    const float* __restrict__ Wself2, const float* __restrict__ Wneigh2,
    char* __restrict__ ws)
{
  int i = blockIdx.x * 256 + threadIdx.x;
  if (i < 65536) { pack512((u16*)(ws + OFF_WIH1P), Wih1, i); return; }
  i -= 65536;
  if (i < 65536) { pack512((u16*)(ws + OFF_WHH1P), Whh1, i); return; }
  i -= 65536;
  if (i < 65536) { pack512((u16*)(ws + OFF_WIH2P), Wih2, i); return; }
  i -= 65536;
  if (i < 65536) { pack512((u16*)(ws + OFF_WHH2P), Whh2, i); return; }
  i -= 65536;
  if (i < 16384) { pack128((u16*)(ws + OFF_WS1P), Wself1, i); return; }
  i -= 16384;
  if (i < 16384) { pack128((u16*)(ws + OFF_WN1P), Wneigh1, i); return; }
  i -= 16384;
  if (i < 128) { ((u16*)(ws + OFF_WS2B))[i] = f2bf(Wself2[i]); return; }
  i -= 128;
  if (i < 128) { ((u16*)(ws + OFF_WN2B))[i] = f2bf(Wneigh2[i]); return; }
  i -= 128;
  if (i < 512) { ((float*)(ws + OFF_B1))[i] = (bih1[i] + bhh1[i]) * gate_scale(i); return; }
  i -= 512;
  if (i < 512) { ((float*)(ws + OFF_B2))[i] = (bih2[i] + bhh2[i]) * gate_scale(i); }
}

// prep1: x fp32 -> x16 bf16, and XpreA = x@Wih1^T + b1 (fp16 gather layout:
// element offset = n*512 + kt*64 + quad*16 + gate*4 + r).
// 625 blocks x 32 rows exact; 8 waves: rg = wave&1 (row half), jh = wave>>1
// (j quarter, 8 tj each). Stage rows padded to 520 u16 (bank-conflict-free).
__global__ __launch_bounds__(512) void prep1_kernel(
    const float* __restrict__ x,    // [NN,128] fp32
    const frag8* __restrict__ Wp,   // Wih1 packed, 8192 frags
    const float* __restrict__ bias, // [512] fp32 prescaled
    u16* __restrict__ x16,          // [NN,128] bf16 out
    u16* __restrict__ xpre)         // [NN,512] fp16 packed out
{
  __shared__ __align__(16) u16 xt[32 * 136];         // 8704 B bf16 input tile
  __shared__ __align__(16) u16 stage[32 * 520];      // 33280 B fp16 out stage
  const int tid = threadIdx.x;
  const int base = blockIdx.x * 32;
  {
    int r = tid >> 4, o = (tid & 15) * 8;            // 32 rows x 16 chunks
    const float* src = x + (size_t)(base + r) * 128 + o;
    float4 v0 = *(const float4*)(src);
    float4 v1 = *(const float4*)(src + 4);
    uint4 st = { pkbf(v0.x, v0.y), pkbf(v0.z, v0.w),
                 pkbf(v1.x, v1.y), pkbf(v1.z, v1.w) };
    *(uint4*)(xt + r * 136 + o) = st;
    *(uint4*)(x16 + (size_t)(base + r) * 128 + o) = st;
  }
  __syncthreads();
  const int lane = tid & 63, wave = tid >> 6;
  const int m = lane & 15, quad = lane >> 4;
  const int rg = wave & 1, jh = wave >> 1;
  const int r = rg * 16 + m;
  frag8 bfr[4];
#pragma unroll
  for (int kb = 0; kb < 4; ++kb)
    bfr[kb] = *(const frag8*)(xt + r * 136 + kb * 32 + quad * 8);
  u16* srow = stage + r * 520;
#pragma unroll
  for (int j = 0; j < 8; ++j) {
    const int tj = jh * 8 + j;
    float4 bv = *(const float4*)(bias + tj * 16 + quad * 4);
    facc4 acc = {bv.x, bv.y, bv.z, bv.w};
#pragma unroll
    for (int kb = 0; kb < 4; ++kb)
      acc = mfma16(Wp[(tj * 4 + kb) * 64 + lane], bfr[kb], acc);
    uint2 st = { pk2h(acc[0], acc[1]), pk2h(acc[2], acc[3]) };
    *(uint2*)(srow + (tj & 7) * 64 + quad * 16 + (tj >> 3) * 4) = st;
  }
  __syncthreads();
#pragma unroll
  for (int i = tid; i < 2048; i += 512) {            // 32 rows x 64 uint4
    int rr = i >> 6, cc = i & 63;
    ((uint4*)(xpre + (size_t)(base + rr) * 512))[cc] =
        ((const uint4*)(stage + rr * 520))[cc];
  }
}

// 16-step LSTM over gathered neighbor sequences, fused output layer(s).
// 8 waves per 16-node group; wave g owns kt-tile g (units 16g..16g+15) for
// all 4 gates; Whh A-fragments in registers (AGPRs); h double-buffered LDS.
// mode 0: epilogue = out1 (h1 = relu(x@Ws^T + h@Wn^T + b)) AND
//         Xpre2 = h1@Wih2^T + b2 -> xpreOut (ping-pong buffer).
// mode 1: epilogue = out2 (sigmoid(h1.ws2 + h.wn2 + b)), writes outp.
__global__ __launch_bounds__(512, 4) void lstm_kernel(
    const u16* __restrict__ Xpre,   // [NN,512] fp16 packed, prescaled, bias folded
    const frag8* __restrict__ Wp,   // packed Whh, 8192 frags
    const int* __restrict__ nbr,    // [NN,16]
    const u16* __restrict__ xin,    // mode0: x16 [NN,128] bf16
    const frag8* __restrict__ Wsp, const frag8* __restrict__ Wnp,  // mode0
    const float* __restrict__ bias_o,                              // mode0
    const frag8* __restrict__ WihX, const float* __restrict__ biasX,// mode0 xpre2
    u16* __restrict__ xpreOut,                                     // mode0 xpre2
    const u16* __restrict__ ws2, const u16* __restrict__ wn2,      // mode1
    const float* __restrict__ b2o,                                 // mode1
    u16* __restrict__ h1,           // mode0 out / mode1 in
    float* __restrict__ outp,       // mode1 out
    int mode)
{
  __shared__ __align__(16) u16 h_lds[2][16 * 136];   // 8704 B double-buffered h
  __shared__ __align__(16) u16 xstage[16 * 520];     // 16640 B xpre2 stage
  const int tid = threadIdx.x;
  const int lane = tid & 63, g = tid >> 6;          // wave g owns kt = g
  const int m = lane & 15, quad = lane >> 4;

  // A-fragments for kt=g: [gate][kb], resident for all 16 steps.
  frag8 A[4][4];
#pragma unroll
  for (int gate = 0; gate < 4; ++gate)
#pragma unroll
    for (int kb = 0; kb < 4; ++kb)
      A[gate][kb] = Wp[((gate * 8 + g) * 4 + kb) * 64 + lane];

  for (int i = tid; i < 16 * 136; i += 512) h_lds[0][i] = 0;

  const int node_base = blockIdx.x * 16;             // 1250*16 == 20000 exact
  // lane holds nbr[node_base + m][quad*4 + s], s=0..3
  int4 idx4 = *(const int4*)(nbr + (size_t)(node_base + m) * 16 + quad * 4);

  facc4 c = {0.f, 0.f, 0.f, 0.f};

  // this lane's 32-byte Xpre slice (kt=g, quad) of neighbor at step t
  auto xslice = [&](int t) -> const uint4* {
    const int tq = t >> 2, ts = t & 3;
    int sel = (ts == 0) ? idx4.x : (ts == 1) ? idx4.y : (ts == 2) ? idx4.z : idx4.w;
    int idx = __shfl(sel, m + (tq << 4), 64);        // neighbor of node m at step t
    return (const uint4*)(Xpre + (size_t)idx * 512) + g * 8 + quad * 2;
  };

  uint4 pX0, pX1;                                    // 1-step-ahead prefetch
  { const uint4* p0 = xslice(0); pX0 = p0[0]; pX1 = p0[1]; }

  __syncthreads();                                   // h zeros + everyone ready

#pragma unroll 1
  for (int t = 0; t < 16; ++t) {
    const u16* hr = h_lds[t & 1];
    u16* hw = h_lds[(t + 1) & 1];
    const uint4* pn = xslice(t < 15 ? t + 1 : 15);   // t=15 re-read is an L2 hit

    frag8 bfr[4];                                    // B = full h (prev step)
#pragma unroll
    for (int kb = 0; kb < 4; ++kb)
      bfr[kb] = *(const frag8*)(hr + m * 136 + kb * 32 + quad * 8);

    union { uint4 u; half8 h; } ua, ub;
    ua.u = pX0; ub.u = pX1;
    facc4 ai = {(float)ua.h[0], (float)ua.h[1], (float)ua.h[2], (float)ua.h[3]};
    facc4 af = {(float)ua.h[4], (float)ua.h[5], (float)ua.h[6], (float)ua.h[7]};
    facc4 ag = {(float)ub.h[0], (float)ub.h[1], (float)ub.h[2], (float)ub.h[3]};
    facc4 ao = {(float)ub.h[4], (float)ub.h[5], (float)ub.h[6], (float)ub.h[7]};
    // refill prefetch: a full step of MFMA+VALU to hide under
    pX0 = pn[0]; pX1 = pn[1];

#pragma unroll
    for (int kb = 0; kb < 4; ++kb) {
      ai = mfma16(A[0][kb], bfr[kb], ai);
      af = mfma16(A[1][kb], bfr[kb], af);
      ag = mfma16(A[2][kb], bfr[kb], ag);
      ao = mfma16(A[3][kb], bfr[kb], ao);
    }

    facc4 hv;
#pragma unroll
    for (int r = 0; r < 4; ++r) {
      float si = sigm_ps(ai[r]);
      float sf = sigm_ps(af[r]);
      float tg = tanh_ps(ag[r]);
      float cn = sf * c[r] + si * tg;
      c[r] = cn;
      float so = sigm_ps(ao[r]);
      hv[r] = so * tanh_ps((2.f * L2E) * cn);
    }
    uint2 hp = { pkbf(hv[0], hv[1]), pkbf(hv[2], hv[3]) };
    *(uint2*)(hw + m * 136 + g * 16 + quad * 4) = hp;
    // LDS-only drain: prefetch vmcnt loads stay in flight across barrier
    asm volatile("s_waitcnt lgkmcnt(0)" ::: "memory");
    __builtin_amdgcn_s_barrier();
  }

  const u16* hf = h_lds[0];                          // final h (16 steps -> buf 0)

  if (mode == 0) {
    // ---- fused out1: h1 = relu(x@Ws^T + h@Wn^T + b), wave g = j-tile g ----
    const int row = node_base + m;
    frag8 bx[4], bh[4];
#pragma unroll
    for (int kb = 0; kb < 4; ++kb) {
      bx[kb] = *(const frag8*)(xin + (size_t)row * 128 + kb * 32 + quad * 8);
      bh[kb] = *(const frag8*)(hf + m * 136 + kb * 32 + quad * 8);
    }
    float4 bv = *(const float4*)(bias_o + g * 16 + quad * 4);
    facc4 acc = {bv.x, bv.y, bv.z, bv.w};
#pragma unroll
    for (int kb = 0; kb < 4; ++kb) {
      frag8 wsk = Wsp[(g * 4 + kb) * 64 + lane];
      acc = mfma16(wsk, bx[kb], acc);
      frag8 wnk = Wnp[(g * 4 + kb) * 64 + lane];
      acc = mfma16(wnk, bh[kb], acc);
    }
    uint2 st = { pkbf(fmaxf(acc[0], 0.f), fmaxf(acc[1], 0.f)),
                 pkbf(fmaxf(acc[2], 0.f), fmaxf(acc[3], 0.f)) };
    u16* stg = (u16*)h_lds[1];                       // free after final barrier
    *(uint2*)(stg + m * 136 + g * 16 + quad * 4) = st;
    __syncthreads();
    {                                                // coalesced h1 write
      const int r = tid >> 5, cc = tid & 31;         // 16 rows x 32 x 8 B
      *(uint2*)(h1 + (size_t)(node_base + r) * 128 + cc * 4) =
          *(const uint2*)(stg + r * 136 + cc * 4);
    }
    // ---- fused xpre2: XpreB = h1@Wih2^T + b2 for our 16 rows ----
    frag8 b2f[4];
#pragma unroll
    for (int kb = 0; kb < 4; ++kb)
      b2f[kb] = *(const frag8*)(stg + m * 136 + kb * 32 + quad * 8);
#pragma unroll
    for (int j = 0; j < 4; ++j) {
      const int tj = g * 4 + j;
      float4 bx2 = *(const float4*)(biasX + tj * 16 + quad * 4);
      facc4 acc2 = {bx2.x, bx2.y, bx2.z, bx2.w};
#pragma unroll
      for (int kb = 0; kb < 4; ++kb)
        acc2 = mfma16(WihX[(tj * 4 + kb) * 64 + lane], b2f[kb], acc2);
      uint2 st2 = { pk2h(acc2[0], acc2[1]), pk2h(acc2[2], acc2[3]) };
      *(uint2*)(xstage + m * 520 + (tj & 7) * 64 + quad * 16 + (tj >> 3) * 4) = st2;
    }
    __syncthreads();
#pragma unroll
    for (int i = tid; i < 1024; i += 512) {          // 16 rows x 64 uint4
      int rr = i >> 6, cc = i & 63;
      ((uint4*)(xpreOut + (size_t)(node_base + rr) * 512))[cc] =
          ((const uint4*)(xstage + rr * 520))[cc];
    }
  } else {
    // ---- fused out2: sigmoid(h1.ws2 + h.wn2 + b), 32 threads/node ----
    const int n = tid >> 5, cc = tid & 31;
    uint2 a = *(const uint2*)(h1 + (size_t)(node_base + n) * 128 + cc * 4);
    uint2 w = *(const uint2*)(ws2 + cc * 4);
    uint2 b = *(const uint2*)(hf + n * 136 + cc * 4);
    uint2 v = *(const uint2*)(wn2 + cc * 4);
    float p = dot2(a.x, w.x) + dot2(a.y, w.y) + dot2(b.x, v.x) + dot2(b.y, v.y);
#pragma unroll
    for (int s = 1; s < 32; s <<= 1) p += __shfl_xor(p, s, 64);
    if (cc == 0) {
      float acc = p + b2o[0];
      outp[node_base + n] =
          __builtin_amdgcn_rcpf(1.f + __builtin_amdgcn_exp2f(-acc * L2E));
    }
  }
}

extern "C" void kernel_launch(void* const* d_in, const int* in_sizes, int n_in,
                              void* d_out, int out_size, void* d_ws, size_t ws_size,
                              hipStream_t stream) {
  const float* x       = (const float*)d_in[0];
  const int*   nbr     = (const int*)d_in[1];
  const float* Wih1    = (const float*)d_in[2];
  const float* Whh1    = (const float*)d_in[3];
  const float* bih1    = (const float*)d_in[4];
  const float* bhh1    = (const float*)d_in[5];
  const float* Wself1  = (const float*)d_in[6];
  const float* Wneigh1 = (const float*)d_in[7];
  const float* bneigh1 = (const float*)d_in[8];
  const float* Wih2    = (const float*)d_in[9];
  const float* Whh2    = (const float*)d_in[10];
  const float* bih2    = (const float*)d_in[11];
  const float* bhh2    = (const float*)d_in[12];
  const float* Wself2  = (const float*)d_in[13];
  const float* Wneigh2 = (const float*)d_in[14];
  const float* bneigh2 = (const float*)d_in[15];

  char* ws = (char*)d_ws;
  u16*   x16   = (u16*)(ws + OFF_X16);
  u16*   h1    = (u16*)(ws + OFF_H1);
  u16*   XpreA = (u16*)(ws + OFF_XPREA);
  u16*   XpreB = (u16*)(ws + OFF_XPREB);
  frag8* Wih1p = (frag8*)(ws + OFF_WIH1P);
  frag8* Whh1p = (frag8*)(ws + OFF_WHH1P);
  frag8* Wih2p = (frag8*)(ws + OFF_WIH2P);
  frag8* Whh2p = (frag8*)(ws + OFF_WHH2P);
  frag8* Ws1p  = (frag8*)(ws + OFF_WS1P);
  frag8* Wn1p  = (frag8*)(ws + OFF_WN1P);
  u16*   Ws2b  = (u16*)(ws + OFF_WS2B);
  u16*   Wn2b  = (u16*)(ws + OFF_WN2B);
  float* b1    = (float*)(ws + OFF_B1);
  float* b2    = (float*)(ws + OFF_B2);

  pack_kernel<<<1157, 256, 0, stream>>>(Wih1, Whh1, bih1, bhh1, Wself1,
                                        Wneigh1, Wih2, Whh2, bih2, bhh2,
                                        Wself2, Wneigh2, ws);
  prep1_kernel<<<625, 512, 0, stream>>>(x, Wih1p, b1, x16, XpreA);
  // layer 1 (+ fused out1 + fused xpre2 -> XpreB)
  lstm_kernel<<<1250, 512, 0, stream>>>(XpreA, Whh1p, nbr, x16, Ws1p, Wn1p,
                                        bneigh1, Wih2p, b2, XpreB,
                                        Ws2b, Wn2b, bneigh2, h1,
                                        (float*)d_out, 0);
  // layer 2 (+ fused out2)
  lstm_kernel<<<1250, 512, 0, stream>>>(XpreB, Whh2p, nbr, x16, Ws1p, Wn1p,
                                        bneigh1, Wih2p, b2, XpreB,
                                        Ws2b, Wn2b, bneigh2, h1,
                                        (float*)d_out, 1);
}

// Round 7
// 238.499 us; speedup vs baseline: 5.3272x; 1.0293x over previous
//
#include <hip/hip_runtime.h>

// ---------------------------------------------------------------------------
// SAGE-LSTM on MI355X.
// Xpre = x@Wih^T + b precomputed per layer (hoists the input GEMM out of the
// 16-step recurrence). LSTM: gates^T = Whh.h^T with MFMA 16x16x32 bf16.
//
// R2: fp16 Xpre + gather layout + 1-step register prefetch (565 -> 117 us).
// R3: pair-split 10 waves/block (117 -> 94 us).
// R4: Whh in registers (AGPRs), 8 waves/group, h double-buffered LDS (77 us).
// R5: LDS-staged coalesced stores; v_cvt_pk_bf16_f32 packing (263 us).
// R6: out1/out2 fused into lstm epilogues (258 us).
// R7: xpre2+out1 fused into lstm1 (ping-pong XpreA/B); prep1 = x-cvt+xpre1;
//     520-u16 stage padding (245 us).
// R8: op-count round (reg-capped at 128 -> only per-step ops left):
//     - per-step __shfl (ds_bpermute, ~23 cy conflict each) -> idx_lds[t][m]
//       broadcast table, written once (all waves share the same indices).
//     - trans fusion: si*tg=(eg-1)*rcp((1+ea)(1+eg)), so*tanh=(C-1)*rcp(
//       (1+eo)(1+C)): 10 -> 8 trans/unit-step; clamp g-arg <= 80 (inf guard).
//     - lstm split into lstm1/lstm2 kernels (no shared fat regalloc).
//     - pack vectorized 8 elems/thread (149 blocks).
// ---------------------------------------------------------------------------

#define NN   20000
#define L2E  1.4426950408889634f

typedef unsigned short u16;
typedef __attribute__((ext_vector_type(8))) short frag8;     // 8 x bf16
typedef __attribute__((ext_vector_type(4))) float facc4;     // 4 x f32 acc
typedef __attribute__((ext_vector_type(8))) _Float16 half8;  // 8 x fp16

// ---- workspace layout (bytes) ----
#define OFF_X16   0u
#define OFF_H1    5120000u
#define OFF_WIH1P 15360000u
#define OFF_WHH1P 15491072u
#define OFF_WIH2P 15622144u
#define OFF_WHH2P 15753216u
#define OFF_WS1P  15884288u
#define OFF_WN1P  15917056u
#define OFF_WS2B  15949824u
#define OFF_WN2B  15950080u
#define OFF_B1    15950336u
#define OFF_B2    15952384u
#define OFF_XPREA 15954432u   // fp16 [NN,512] = 20,480,000 B
#define OFF_XPREB 36434432u   // fp16 [NN,512] = 20,480,000 B (ends 56,914,432)

__device__ __forceinline__ u16 f2bf(float f) {
  union { float f; unsigned u; } v; v.f = f;
  unsigned r = (v.u + 0x7fffu + ((v.u >> 16) & 1u)) >> 16;  // RNE
  return (u16)r;
}
__device__ __forceinline__ float bflo(unsigned u) {
  union { unsigned u; float f; } v; v.u = u << 16; return v.f;
}
__device__ __forceinline__ float bfhi(unsigned u) {
  union { unsigned u; float f; } v; v.u = u & 0xffff0000u; return v.f;
}
__device__ __forceinline__ unsigned pk2h(float a, float b) {
  union { _Float16 h[2]; unsigned u; } v;
  v.h[0] = (_Float16)a; v.h[1] = (_Float16)b;
  return v.u;
}
// RNE f32x2 -> packed bf16x2 in one HW op (no builtin on gfx950 -> asm)
__device__ __forceinline__ unsigned pkbf(float a, float b) {
  unsigned r;
  asm("v_cvt_pk_bf16_f32 %0, %1, %2" : "=v"(r) : "v"(a), "v"(b));
  return r;
}
__device__ __forceinline__ facc4 mfma16(frag8 a, frag8 b, facc4 c) {
  return __builtin_amdgcn_mfma_f32_16x16x32_bf16(a, b, c, 0, 0, 0);
}
__device__ __forceinline__ float rcpf(float x) { return __builtin_amdgcn_rcpf(x); }
__device__ __forceinline__ float ex2(float x)  { return __builtin_amdgcn_exp2f(x); }
// x prescaled by L2E: sigmoid(x) = 1/(1+2^-xp)
__device__ __forceinline__ float sigm_ps(float xp) { return rcpf(1.f + ex2(-xp)); }
__device__ __forceinline__ float gate_scale(int row) {
  return (row >= 256 && row < 384) ? 2.f * L2E : L2E;  // g-gate rows get 2*log2e
}
__device__ __forceinline__ float dot2(unsigned a, unsigned b) {
  return bflo(a) * bflo(b) + bfhi(a) * bfhi(b);
}

// vectorized pack: frag f covers A[row][col..col+7] contiguous fp32.
// frag layout: f = (tj*4+kb)*64 + ln ; row = tj*16+(ln&15), col = kb*32+(ln>>4)*8
__device__ __forceinline__ void pack512v(frag8* dst, const float* src, int f) {
  int ln = f & 63, kb = (f >> 6) & 3, tj = f >> 8;
  int row = tj * 16 + (ln & 15);
  int col = kb * 32 + (ln >> 4) * 8;
  float s = gate_scale(row);
  const float* p = src + row * 128 + col;
  float4 v0 = *(const float4*)p;
  float4 v1 = *(const float4*)(p + 4);
  uint4 u = { pkbf(v0.x * s, v0.y * s), pkbf(v0.z * s, v0.w * s),
              pkbf(v1.x * s, v1.y * s), pkbf(v1.z * s, v1.w * s) };
  *(uint4*)&dst[f] = u;
}
__device__ __forceinline__ void pack128v(frag8* dst, const float* src, int f) {
  int ln = f & 63, kb = (f >> 6) & 3, tj = f >> 8;
  const float* p = src + (tj * 16 + (ln & 15)) * 128 + kb * 32 + (ln >> 4) * 8;
  float4 v0 = *(const float4*)p;
  float4 v1 = *(const float4*)(p + 4);
  uint4 u = { pkbf(v0.x, v0.y), pkbf(v0.z, v0.w),
              pkbf(v1.x, v1.y), pkbf(v1.z, v1.w) };
  *(uint4*)&dst[f] = u;
}

// 149 blocks x 256 = 38144 threads exact.
__global__ __launch_bounds__(256) void pack_kernel(
    const float* __restrict__ Wih1, const float* __restrict__ Whh1,
    const float* __restrict__ bih1, const float* __restrict__ bhh1,
    const float* __restrict__ Wself1, const float* __restrict__ Wneigh1,
    const float* __restrict__ Wih2, const float* __restrict__ Whh2,
    const float* __restrict__ bih2, const float* __restrict__ bhh2,
    const float* __restrict__ Wself2, const float* __restrict__ Wneigh2,
    char* __restrict__ ws)
{
  int i = blockIdx.x * 256 + threadIdx.x;
  if (i < 8192) { pack512v((frag8*)(ws + OFF_WIH1P), Wih1, i); return; }
  i -= 8192;
  if (i < 8192) { pack512v((frag8*)(ws + OFF_WHH1P), Whh1, i); return; }
  i -= 8192;
  if (i < 8192) { pack512v((frag8*)(ws + OFF_WIH2P), Wih2, i); return; }
  i -= 8192;
  if (i < 8192) { pack512v((frag8*)(ws + OFF_WHH2P), Whh2, i); return; }
  i -= 8192;
  if (i < 2048) { pack128v((frag8*)(ws + OFF_WS1P), Wself1, i); return; }
  i -= 2048;
  if (i < 2048) { pack128v((frag8*)(ws + OFF_WN1P), Wneigh1, i); return; }
  i -= 2048;
  if (i < 128) { ((u16*)(ws + OFF_WS2B))[i] = f2bf(Wself2[i]); return; }
  i -= 128;
  if (i < 128) { ((u16*)(ws + OFF_WN2B))[i] = f2bf(Wneigh2[i]); return; }
  i -= 128;
  if (i < 512) { ((float*)(ws + OFF_B1))[i] = (bih1[i] + bhh1[i]) * gate_scale(i); return; }
  i -= 512;
  if (i < 512) { ((float*)(ws + OFF_B2))[i] = (bih2[i] + bhh2[i]) * gate_scale(i); }
}

// prep1: x fp32 -> x16 bf16, and XpreA = x@Wih1^T + b1 (fp16 gather layout:
// element offset = n*512 + kt*64 + quad*16 + gate*4 + r).
__global__ __launch_bounds__(512) void prep1_kernel(
    const float* __restrict__ x,    // [NN,128] fp32
    const frag8* __restrict__ Wp,   // Wih1 packed, 8192 frags
    const float* __restrict__ bias, // [512] fp32 prescaled
    u16* __restrict__ x16,          // [NN,128] bf16 out
    u16* __restrict__ xpre)         // [NN,512] fp16 packed out
{
  __shared__ __align__(16) u16 xt[32 * 136];         // 8704 B bf16 input tile
  __shared__ __align__(16) u16 stage[32 * 520];      // 33280 B fp16 out stage
  const int tid = threadIdx.x;
  const int base = blockIdx.x * 32;
  {
    int r = tid >> 4, o = (tid & 15) * 8;            // 32 rows x 16 chunks
    const float* src = x + (size_t)(base + r) * 128 + o;
    float4 v0 = *(const float4*)(src);
    float4 v1 = *(const float4*)(src + 4);
    uint4 st = { pkbf(v0.x, v0.y), pkbf(v0.z, v0.w),
                 pkbf(v1.x, v1.y), pkbf(v1.z, v1.w) };
    *(uint4*)(xt + r * 136 + o) = st;
    *(uint4*)(x16 + (size_t)(base + r) * 128 + o) = st;
  }
  __syncthreads();
  const int lane = tid & 63, wave = tid >> 6;
  const int m = lane & 15, quad = lane >> 4;
  const int rg = wave & 1, jh = wave >> 1;
  const int r = rg * 16 + m;
  frag8 bfr[4];
#pragma unroll
  for (int kb = 0; kb < 4; ++kb)
    bfr[kb] = *(const frag8*)(xt + r * 136 + kb * 32 + quad * 8);
  u16* srow = stage + r * 520;
#pragma unroll
  for (int j = 0; j < 8; ++j) {
    const int tj = jh * 8 + j;
    float4 bv = *(const float4*)(bias + tj * 16 + quad * 4);
    facc4 acc = {bv.x, bv.y, bv.z, bv.w};
#pragma unroll
    for (int kb = 0; kb < 4; ++kb)
      acc = mfma16(Wp[(tj * 4 + kb) * 64 + lane], bfr[kb], acc);
    uint2 st = { pk2h(acc[0], acc[1]), pk2h(acc[2], acc[3]) };
    *(uint2*)(srow + (tj & 7) * 64 + quad * 16 + (tj >> 3) * 4) = st;
  }
  __syncthreads();
#pragma unroll
  for (int i = tid; i < 2048; i += 512) {            // 32 rows x 64 uint4
    int rr = i >> 6, cc = i & 63;
    ((uint4*)(xpre + (size_t)(base + rr) * 512))[cc] =
        ((const uint4*)(stage + rr * 520))[cc];
  }
}

// shared LSTM core: 16 steps, h double-buffered in h_lds, final h -> h_lds[0].
// 8 waves per 16-node group; wave g owns kt-tile g for all 4 gates; Whh
// A-fragments in registers (AGPRs). idx_lds[t][m] broadcast table replaces
// per-step ds_bpermute. Fused nonlinearity: 8 trans/unit-step.
__device__ __forceinline__ void lstm_core(
    const u16* __restrict__ Xpre, const frag8* __restrict__ Wp,
    const int* __restrict__ nbr, int node_base,
    u16 (*h_lds)[16 * 136], int (*idx_lds)[16])
{
  const int tid = threadIdx.x;
  const int lane = tid & 63, g = tid >> 6;
  const int m = lane & 15, quad = lane >> 4;

  frag8 A[4][4];
#pragma unroll
  for (int gate = 0; gate < 4; ++gate)
#pragma unroll
    for (int kb = 0; kb < 4; ++kb)
      A[gate][kb] = Wp[((gate * 8 + g) * 4 + kb) * 64 + lane];

  for (int i = tid; i < 16 * 136; i += 512) h_lds[0][i] = 0;

  // lane holds nbr[node_base + m][quad*4 + s], s=0..3
  int4 idx4 = *(const int4*)(nbr + (size_t)(node_base + m) * 16 + quad * 4);
  if (g == 0) {                                      // all waves share indices
    idx_lds[quad * 4 + 0][m] = idx4.x;
    idx_lds[quad * 4 + 1][m] = idx4.y;
    idx_lds[quad * 4 + 2][m] = idx4.z;
    idx_lds[quad * 4 + 3][m] = idx4.w;
  }

  facc4 c = {0.f, 0.f, 0.f, 0.f};

  // initial prefetch (t=0) via shfl (idx_lds not yet visible)
  int idx0 = __shfl(idx4.x, m, 64);
  const uint4* p0 = (const uint4*)(Xpre + (size_t)idx0 * 512) + g * 8 + quad * 2;
  uint4 pX0 = p0[0], pX1 = p0[1];

  __syncthreads();                                   // h zeros + idx_lds ready

#pragma unroll 1
  for (int t = 0; t < 16; ++t) {
    const u16* hr = h_lds[t & 1];
    u16* hw = h_lds[(t + 1) & 1];
    int idxn = idx_lds[t < 15 ? t + 1 : 15][m];      // broadcast read (4 lanes/addr)
    const uint4* pn = (const uint4*)(Xpre + (size_t)idxn * 512) + g * 8 + quad * 2;

    frag8 bfr[4];                                    // B = full h (prev step)
#pragma unroll
    for (int kb = 0; kb < 4; ++kb)
      bfr[kb] = *(const frag8*)(hr + m * 136 + kb * 32 + quad * 8);

    union { uint4 u; half8 h; } ua, ub;
    ua.u = pX0; ub.u = pX1;
    facc4 ai = {(float)ua.h[0], (float)ua.h[1], (float)ua.h[2], (float)ua.h[3]};
    facc4 af = {(float)ua.h[4], (float)ua.h[5], (float)ua.h[6], (float)ua.h[7]};
    facc4 ag = {(float)ub.h[0], (float)ub.h[1], (float)ub.h[2], (float)ub.h[3]};
    facc4 ao = {(float)ub.h[4], (float)ub.h[5], (float)ub.h[6], (float)ub.h[7]};
    // refill prefetch: a full step of MFMA+VALU to hide under
    pX0 = pn[0]; pX1 = pn[1];

#pragma unroll
    for (int kb = 0; kb < 4; ++kb) {
      ai = mfma16(A[0][kb], bfr[kb], ai);
      af = mfma16(A[1][kb], bfr[kb], af);
      ag = mfma16(A[2][kb], bfr[kb], ag);
      ao = mfma16(A[3][kb], bfr[kb], ao);
    }

    facc4 hv;
#pragma unroll
    for (int r = 0; r < 4; ++r) {
      // fused: si*tg = (eg-1)*rcp((1+ea)(1+eg)); so*tanh(c') = (C-1)*rcp((1+eo)(1+C))
      float ea = ex2(-ai[r]);
      float eg = ex2(fminf(ag[r], 80.f));            // inf guard for numerator
      float sitg = (eg - 1.f) * rcpf((1.f + ea) * (1.f + eg));
      float sf = sigm_ps(af[r]);
      float cn = sf * c[r] + sitg;
      c[r] = cn;
      float eo = ex2(-ao[r]);
      float C  = ex2((2.f * L2E) * cn);
      hv[r] = (C - 1.f) * rcpf((1.f + eo) * (1.f + C));
    }
    uint2 hp = { pkbf(hv[0], hv[1]), pkbf(hv[2], hv[3]) };
    *(uint2*)(hw + m * 136 + g * 16 + quad * 4) = hp;
    // LDS-only drain: prefetch vmcnt loads stay in flight across barrier
    asm volatile("s_waitcnt lgkmcnt(0)" ::: "memory");
    __builtin_amdgcn_s_barrier();
  }
}

// lstm1: core + fused out1 (h1 = relu(x@Ws^T + h@Wn^T + b)) + fused
// xpre2 (XpreB = h1@Wih2^T + b2, gather layout, ping-pong buffer).
__global__ __launch_bounds__(512, 4) void lstm1_kernel(
    const u16* __restrict__ Xpre, const frag8* __restrict__ Wp,
    const int* __restrict__ nbr, const u16* __restrict__ xin,
    const frag8* __restrict__ Wsp, const frag8* __restrict__ Wnp,
    const float* __restrict__ bias_o,
    const frag8* __restrict__ WihX, const float* __restrict__ biasX,
    u16* __restrict__ xpreOut, u16* __restrict__ h1)
{
  __shared__ __align__(16) u16 h_lds[2][16 * 136];   // 8704 B
  __shared__ int idx_lds[16][16];                    // 1024 B
  __shared__ __align__(16) u16 xstage[16 * 520];     // 16640 B
  const int tid = threadIdx.x;
  const int lane = tid & 63, g = tid >> 6;
  const int m = lane & 15, quad = lane >> 4;
  const int node_base = blockIdx.x * 16;             // 1250*16 == 20000 exact

  lstm_core(Xpre, Wp, nbr, node_base, h_lds, idx_lds);
  const u16* hf = h_lds[0];

  // ---- fused out1: wave g = j-tile g ----
  const int row = node_base + m;
  frag8 bx[4], bh[4];
#pragma unroll
  for (int kb = 0; kb < 4; ++kb) {
    bx[kb] = *(const frag8*)(xin + (size_t)row * 128 + kb * 32 + quad * 8);
    bh[kb] = *(const frag8*)(hf + m * 136 + kb * 32 + quad * 8);
  }
  float4 bv = *(const float4*)(bias_o + g * 16 + quad * 4);
  facc4 acc = {bv.x, bv.y, bv.z, bv.w};
#pragma unroll
  for (int kb = 0; kb < 4; ++kb) {
    acc = mfma16(Wsp[(g * 4 + kb) * 64 + lane], bx[kb], acc);
    acc = mfma16(Wnp[(g * 4 + kb) * 64 + lane], bh[kb], acc);
  }
  uint2 st = { pkbf(fmaxf(acc[0], 0.f), fmaxf(acc[1], 0.f)),
               pkbf(fmaxf(acc[2], 0.f), fmaxf(acc[3], 0.f)) };
  u16* stg = (u16*)h_lds[1];                         // free after final barrier
  *(uint2*)(stg + m * 136 + g * 16 + quad * 4) = st;
  __syncthreads();
  {                                                  // coalesced h1 write
    const int r = tid >> 5, cc = tid & 31;           // 16 rows x 32 x 8 B
    *(uint2*)(h1 + (size_t)(node_base + r) * 128 + cc * 4) =
        *(const uint2*)(stg + r * 136 + cc * 4);
  }
  // ---- fused xpre2: XpreB = h1@Wih2^T + b2 for our 16 rows ----
  frag8 b2f[4];
#pragma unroll
  for (int kb = 0; kb < 4; ++kb)
    b2f[kb] = *(const frag8*)(stg + m * 136 + kb * 32 + quad * 8);
#pragma unroll
  for (int j = 0; j < 4; ++j) {
    const int tj = g * 4 + j;
    float4 bx2 = *(const float4*)(biasX + tj * 16 + quad * 4);
    facc4 acc2 = {bx2.x, bx2.y, bx2.z, bx2.w};
#pragma unroll
    for (int kb = 0; kb < 4; ++kb)
      acc2 = mfma16(WihX[(tj * 4 + kb) * 64 + lane], b2f[kb], acc2);
    uint2 st2 = { pk2h(acc2[0], acc2[1]), pk2h(acc2[2], acc2[3]) };
    *(uint2*)(xstage + m * 520 + (tj & 7) * 64 + quad * 16 + (tj >> 3) * 4) = st2;
  }
  __syncthreads();
#pragma unroll
  for (int i = tid; i < 1024; i += 512) {            // 16 rows x 64 uint4
    int rr = i >> 6, cc = i & 63;
    ((uint4*)(xpreOut + (size_t)(node_base + rr) * 512))[cc] =
        ((const uint4*)(xstage + rr * 520))[cc];
  }
}

// lstm2: core + fused out2 (sigmoid(h1.ws2 + h.wn2 + b)), 32 threads/node.
__global__ __launch_bounds__(512, 4) void lstm2_kernel(
    const u16* __restrict__ Xpre, const frag8* __restrict__ Wp,
    const int* __restrict__ nbr,
    const u16* __restrict__ ws2, const u16* __restrict__ wn2,
    const float* __restrict__ b2o,
    const u16* __restrict__ h1, float* __restrict__ outp)
{
  __shared__ __align__(16) u16 h_lds[2][16 * 136];   // 8704 B
  __shared__ int idx_lds[16][16];                    // 1024 B
  const int tid = threadIdx.x;
  const int node_base = blockIdx.x * 16;

  lstm_core(Xpre, Wp, nbr, node_base, h_lds, idx_lds);
  const u16* hf = h_lds[0];

  const int n = tid >> 5, cc = tid & 31;
  uint2 a = *(const uint2*)(h1 + (size_t)(node_base + n) * 128 + cc * 4);
  uint2 w = *(const uint2*)(ws2 + cc * 4);
  uint2 b = *(const uint2*)(hf + n * 136 + cc * 4);
  uint2 v = *(const uint2*)(wn2 + cc * 4);
  float p = dot2(a.x, w.x) + dot2(a.y, w.y) + dot2(b.x, v.x) + dot2(b.y, v.y);
#pragma unroll
  for (int s = 1; s < 32; s <<= 1) p += __shfl_xor(p, s, 64);
  if (cc == 0) {
    float acc = p + b2o[0];
    outp[node_base + n] = rcpf(1.f + ex2(-acc * L2E));
  }
}

extern "C" void kernel_launch(void* const* d_in, const int* in_sizes, int n_in,
                              void* d_out, int out_size, void* d_ws, size_t ws_size,
                              hipStream_t stream) {
  const float* x       = (const float*)d_in[0];
  const int*   nbr     = (const int*)d_in[1];
  const float* Wih1    = (const float*)d_in[2];
  const float* Whh1    = (const float*)d_in[3];
  const float* bih1    = (const float*)d_in[4];
  const float* bhh1    = (const float*)d_in[5];
  const float* Wself1  = (const float*)d_in[6];
  const float* Wneigh1 = (const float*)d_in[7];
  const float* bneigh1 = (const float*)d_in[8];
  const float* Wih2    = (const float*)d_in[9];
  const float* Whh2    = (const float*)d_in[10];
  const float* bih2    = (const float*)d_in[11];
  const float* bhh2    = (const float*)d_in[12];
  const float* Wself2  = (const float*)d_in[13];
  const float* Wneigh2 = (const float*)d_in[14];
  const float* bneigh2 = (const float*)d_in[15];

  char* ws = (char*)d_ws;
  u16*   x16   = (u16*)(ws + OFF_X16);
  u16*   h1    = (u16*)(ws + OFF_H1);
  u16*   XpreA = (u16*)(ws + OFF_XPREA);
  u16*   XpreB = (u16*)(ws + OFF_XPREB);
  frag8* Wih1p = (frag8*)(ws + OFF_WIH1P);
  frag8* Whh1p = (frag8*)(ws + OFF_WHH1P);
  frag8* Wih2p = (frag8*)(ws + OFF_WIH2P);
  frag8* Whh2p = (frag8*)(ws + OFF_WHH2P);
  frag8* Ws1p  = (frag8*)(ws + OFF_WS1P);
  frag8* Wn1p  = (frag8*)(ws + OFF_WN1P);
  u16*   Ws2b  = (u16*)(ws + OFF_WS2B);
  u16*   Wn2b  = (u16*)(ws + OFF_WN2B);
  float* b1    = (float*)(ws + OFF_B1);
  float* b2    = (float*)(ws + OFF_B2);

  pack_kernel<<<149, 256, 0, stream>>>(Wih1, Whh1, bih1, bhh1, Wself1,
                                       Wneigh1, Wih2, Whh2, bih2, bhh2,
                                       Wself2, Wneigh2, ws);
  prep1_kernel<<<625, 512, 0, stream>>>(x, Wih1p, b1, x16, XpreA);
  // layer 1 (+ fused out1 + fused xpre2 -> XpreB)
  lstm1_kernel<<<1250, 512, 0, stream>>>(XpreA, Whh1p, nbr, x16, Ws1p, Wn1p,
                                         bneigh1, Wih2p, b2, XpreB, h1);
  // layer 2 (+ fused out2)
  lstm2_kernel<<<1250, 512, 0, stream>>>(XpreB, Whh2p, nbr, Ws2b, Wn2b,
                                         bneigh2, h1, (float*)d_out);
}